// Round 4
// baseline (685.061 us; speedup 1.0000x reference)
//
#include <hip/hip_runtime.h>
#include <math.h>
#include <stdint.h>

#define NB 16
#define NN 50000
#define NC 8
#define ND 2
#define MAX_DET 300
#define NMS_T 0.5f
#define SCORE_T 0.05f
#define CAP 4096
#define TARGET 2048
#define CHUNK 256
#define NT 512          // nms / topk block size
#define HT 8            // tiles per image for hist/compact
#define NPI (NN * NC)   // floats per image = 400000
#define F4PT (NPI / 4 / HT)  // float4s per tile = 12500

typedef unsigned long long u64;

__device__ __forceinline__ float neg_inf() { return -__builtin_inff(); }

// IoU in the reference's exact op order; _rn forbids FMA contraction.
__device__ __forceinline__ float iou_ref(float ax1, float ay1, float ax2, float ay2,
                                         float area_a,
                                         float bx1, float by1, float bx2, float by2) {
    float x1 = fmaxf(ax1, bx1), y1 = fmaxf(ay1, by1);
    float x2 = fminf(ax2, bx2), y2 = fminf(ay2, by2);
    float inter = __fmul_rn(fmaxf(__fsub_rn(x2, x1), 0.0f),
                            fmaxf(__fsub_rn(y2, y1), 0.0f));
    float area_b = __fmul_rn(__fsub_rn(bx2, bx1), __fsub_rn(by2, by1));
    float uni = __fsub_rn(__fadd_rn(area_a, area_b), inter);
    return __fdiv_rn(inter, fmaxf(uni, 1e-8f));
}

// ---------------- Z: zero hist + counters --------------------------------
__global__ void zero_kernel(int* __restrict__ p, int n) {
    int i = blockIdx.x * blockDim.x + threadIdx.x;
    if (i < n) p[i] = 0;
}

// ---------------- H: coalesced histogram ---------------------------------
__global__ __launch_bounds__(1024) void hist_kernel(
    const float* __restrict__ cls, int* __restrict__ hist_g)
{
    __shared__ int hl[8 * 256];
    const int b = blockIdx.x >> 3, t = blockIdx.x & 7;
    const int tid = threadIdx.x;
    for (int i = tid; i < 2048; i += 1024) hl[i] = 0;
    __syncthreads();
    const float4* c4 = (const float4*)(cls + (size_t)b * NPI);
    const int f0 = t * F4PT;
    for (int f = f0 + tid; f < f0 + F4PT; f += 1024) {
        float4 v = c4[f];
        int cb = (f & 1) * 4;
        float vv[4] = {v.x, v.y, v.z, v.w};
        #pragma unroll
        for (int k = 0; k < 4; ++k) {
            float s = vv[k];
            if (s > SCORE_T) {
                int bn = (int)(s * 256.0f); bn = bn > 255 ? 255 : bn;
                atomicAdd(&hl[(cb + k) * 256 + bn], 1);
            }
        }
    }
    __syncthreads();
    for (int i = tid; i < 2048; i += 1024) {
        int v = hl[i];
        if (v) atomicAdd(&hist_g[b * 2048 + i], v);
    }
}

// ---------------- X: per-(b,c) cut + total -------------------------------
__global__ void cut_kernel(const int* __restrict__ hist_g,
                           int* __restrict__ cut_g, int* __restrict__ tot_g)
{
    int bc = threadIdx.x;          // 128 threads
    const int* h = hist_g + bc * 256;
    int total = 0;
    for (int i = 0; i < 256; ++i) total += h[i];
    int suff = 0, cut = 0;
    for (int bn = 255; bn >= 0; --bn) {
        suff += h[bn];
        if (suff >= TARGET) { cut = bn; break; }
    }
    cut_g[bc] = cut; tot_g[bc] = total;
}

// ---------------- C: coalesced compaction --------------------------------
__global__ __launch_bounds__(1024) void compact_kernel(
    const float* __restrict__ cls, const int* __restrict__ cut_g,
    int* __restrict__ cnt_g, u64* __restrict__ cand)
{
    __shared__ int cuts[8];
    const int b = blockIdx.x >> 3, t = blockIdx.x & 7;
    const int tid = threadIdx.x;
    if (tid < 8) cuts[tid] = cut_g[b * 8 + tid];
    __syncthreads();
    const float4* c4 = (const float4*)(cls + (size_t)b * NPI);
    const int f0 = t * F4PT;
    for (int f = f0 + tid; f < f0 + F4PT; f += 1024) {
        float4 v = c4[f];
        int cb = (f & 1) * 4;
        int n = f >> 1;
        float vv[4] = {v.x, v.y, v.z, v.w};
        #pragma unroll
        for (int k = 0; k < 4; ++k) {
            float s = vv[k];
            if (s > SCORE_T) {
                int bn = (int)(s * 256.0f); bn = bn > 255 ? 255 : bn;
                int c = cb + k;
                if (bn >= cuts[c]) {
                    unsigned u = __float_as_uint(s);
                    u ^= (u & 0x80000000u) ? 0xFFFFFFFFu : 0x80000000u;
                    u64 key = ((u64)u << 32) | (unsigned)(~(unsigned)n);
                    int pos = atomicAdd(&cnt_g[b * 8 + c], 1);
                    if (pos < CAP) cand[(size_t)(b * 8 + c) * CAP + pos] = key;
                }
            }
        }
    }
}

// ---------------- N: sort + chunked greedy NMS ---------------------------
__global__ __launch_bounds__(NT) void nms_kernel(
    const float* __restrict__ boxes, const float* __restrict__ cls,
    const u64* __restrict__ cand, const int* __restrict__ cnt_g,
    const int* __restrict__ tot_g,
    int* __restrict__ sel_idx, float* __restrict__ sel_score)
{
    const int bc = blockIdx.x;
    const int b = bc >> 3, c = bc & 7;
    const int tid = threadIdx.x;
    const float4* bx4 = (const float4*)(boxes + (size_t)b * NN * 4);
    const float* sc = cls + (size_t)b * NN * NC + c;   // fallback only
    int* si = sel_idx + bc * MAX_DET;
    float* ss = sel_score + bc * MAX_DET;

    __shared__ u64 keys[CAP];                  // 32 KB (aliased as fallback bitmask)
    __shared__ u64 M[4][CHUNK];                // 8 KB
    __shared__ float4 cbox[CHUNK];
    __shared__ float carea[CHUNK];
    __shared__ int   cidx[CHUNK];
    __shared__ float cscore[CHUNK];
    __shared__ unsigned presup[CHUNK];
    __shared__ u64 accmask_s[4];
    __shared__ float4 abox[MAX_DET];
    __shared__ float aarea[MAX_DET];
    __shared__ float rv[NT];
    __shared__ int   ri[NT];
    __shared__ float sboxsh[5];

    const int cnt = cnt_g[bc], total = tot_g[bc];
    const bool full_fb = (cnt > CAP);
    const int inSet = cnt < CAP ? cnt : CAP;

    int n_acc = 0;
    if (!full_fb) {
        for (int i = tid; i < CAP; i += NT)
            keys[i] = (i < inSet) ? cand[(size_t)bc * CAP + i] : 0ull;
        __syncthreads();

        // bitonic sort descending: (score desc, idx asc)
        for (int k = 2; k <= CAP; k <<= 1) {
            for (int j = k >> 1; j > 0; j >>= 1) {
                for (int p = tid; p < CAP / 2; p += NT) {
                    int i = 2 * p - (p & (j - 1));
                    int ix = i + j;
                    bool dir = ((i & k) == 0);
                    u64 a = keys[i], bq = keys[ix];
                    if ((a < bq) == dir) { keys[i] = bq; keys[ix] = a; }
                }
                __syncthreads();
            }
        }

        // chunked matrix greedy accept
        int base = 0;
        while (n_acc < MAX_DET && base < inSet) {
            int m = inSet - base; if (m > CHUNK) m = CHUNK;

            if (tid < CHUNK) {
                if (tid < m) {
                    u64 key = keys[base + tid];
                    int idx = (int)(~(unsigned)key);
                    unsigned u = (unsigned)(key >> 32);
                    unsigned uo = (u & 0x80000000u) ? (u ^ 0x80000000u) : (~u);
                    float4 bb = bx4[idx];
                    cbox[tid] = bb;
                    carea[tid] = __fmul_rn(__fsub_rn(bb.z, bb.x), __fsub_rn(bb.w, bb.y));
                    cidx[tid] = idx; cscore[tid] = __uint_as_float(uo);
                    presup[tid] = 0u;
                } else presup[tid] = 1u;
            }
            __syncthreads();

            {
                int i = tid & (CHUNK - 1);
                int half = tid >> 8;               // 0 or 1
                if (i < m) {
                    float4 B = cbox[i];
                    unsigned p = 0;
                    for (int t = half; t < n_acc; t += 2) {
                        float4 A = abox[t];
                        if (iou_ref(A.x, A.y, A.z, A.w, aarea[t],
                                    B.x, B.y, B.z, B.w) > NMS_T) { p = 1; break; }
                    }
                    if (p) atomicOr(&presup[i], 1u);
                    for (int w = half * 2; w < half * 2 + 2; ++w) {
                        u64 bits = 0;
                        int j0 = w * 64;
                        for (int jj = 0; jj < 64; ++jj) {
                            int j = j0 + jj;
                            if (j < m && j != i) {
                                float4 A = cbox[j];
                                if (iou_ref(A.x, A.y, A.z, A.w, carea[j],
                                            B.x, B.y, B.z, B.w) > NMS_T)
                                    bits |= 1ull << jj;
                            }
                        }
                        M[w][i] = bits;
                    }
                }
            }
            __syncthreads();

            if (tid < 64) {
                u64 a0 = 0, a1 = 0, a2 = 0, a3 = 0;
                int ngroups = (m + 63) >> 6;
                for (int g = 0; g < ngroups; ++g) {
                    int i = g * 64 + tid;
                    unsigned pe = 1; u64 mg = 0;
                    if (i < m) {
                        pe = presup[i];
                        mg = M[g][i];
                        u64 fold = 0;
                        if (g > 0) fold |= M[0][i] & a0;
                        if (g > 1) fold |= M[1][i] & a1;
                        if (g > 2) fold |= M[2][i] & a2;
                        if (fold) pe = 1;
                    }
                    u64 accw = 0;
                    for (int l = 0; l < 64; ++l) {
                        u64 mgl = __shfl(mg, l, 64);
                        unsigned pel = __shfl(pe, l, 64);
                        if (!pel && (mgl & accw) == 0ull) accw |= 1ull << l;
                    }
                    if (g == 0) a0 = accw; else if (g == 1) a1 = accw;
                    else if (g == 2) a2 = accw; else a3 = accw;
                }
                if (tid == 0) {
                    accmask_s[0] = a0; accmask_s[1] = a1;
                    accmask_s[2] = a2; accmask_s[3] = a3;
                }
            }
            __syncthreads();

            u64 a0 = accmask_s[0], a1 = accmask_s[1], a2 = accmask_s[2], a3 = accmask_s[3];
            int add = __popcll(a0) + __popcll(a1) + __popcll(a2) + __popcll(a3);
            if (tid < m) {
                int g = tid >> 6, o = tid & 63;
                u64 aw = (g == 0) ? a0 : (g == 1) ? a1 : (g == 2) ? a2 : a3;
                if ((aw >> o) & 1ull) {
                    int rank = 0;
                    if (g > 0) rank += __popcll(a0);
                    if (g > 1) rank += __popcll(a1);
                    if (g > 2) rank += __popcll(a2);
                    rank += __popcll(aw & ((1ull << o) - 1ull));
                    int pos = n_acc + rank;
                    if (pos < MAX_DET) {
                        abox[pos] = cbox[tid]; aarea[pos] = carea[tid];
                        si[pos] = cidx[tid]; ss[pos] = cscore[tid];
                    }
                }
            }
            n_acc += add; if (n_acc > MAX_DET) n_acc = MAX_DET;
            base += m;
            __syncthreads();
        }
    }

    const bool part_fb = (!full_fb) && (n_acc < MAX_DET) && (total > inSet);

    if (full_fb || part_fb) {
        // exact fallback; suppression bitmask lives in LDS (aliases keys[])
        unsigned* bm = (unsigned*)keys;
        const int BMW = (NN + 31) / 32;
        for (int i = tid; i < BMW; i += NT) bm[i] = 0u;
        __syncthreads();
        if (full_fb) {
            n_acc = 0;
        } else {
            for (int n = tid; n < NN; n += NT) {
                float4 bbn = bx4[n];
                int s = 0;
                for (int t = 0; t < n_acc; ++t) {
                    float4 A = abox[t];
                    if (iou_ref(A.x, A.y, A.z, A.w, aarea[t],
                                bbn.x, bbn.y, bbn.z, bbn.w) > NMS_T) s = 1;
                }
                if (s) atomicOr(&bm[n >> 5], 1u << (n & 31));
            }
        }
        __syncthreads();

        for (int k = n_acc; k < MAX_DET; ++k) {
            float bv = neg_inf(); int bi = 0x7fffffff;
            for (int n = tid; n < NN; n += NT) {
                if (!((bm[n >> 5] >> (n & 31)) & 1u)) {
                    float v = sc[(size_t)n * NC];
                    if (v > SCORE_T && v > bv) { bv = v; bi = n; }
                }
            }
            rv[tid] = bv; ri[tid] = bi;
            __syncthreads();
            for (int s = NT / 2; s > 0; s >>= 1) {
                if (tid < s) {
                    float ov = rv[tid + s]; int oi = ri[tid + s];
                    if (ov > rv[tid] || (ov == rv[tid] && oi < ri[tid])) { rv[tid] = ov; ri[tid] = oi; }
                }
                __syncthreads();
            }
            float mval = rv[0]; int midx = ri[0];
            if (mval == neg_inf()) {
                for (int kk = k + tid; kk < MAX_DET; kk += NT) { si[kk] = 0; ss[kk] = neg_inf(); }
                break;
            }
            if (tid == 0) {
                si[k] = midx; ss[k] = mval;
                float4 sb = bx4[midx];
                sboxsh[0] = sb.x; sboxsh[1] = sb.y; sboxsh[2] = sb.z; sboxsh[3] = sb.w;
                sboxsh[4] = __fmul_rn(__fsub_rn(sb.z, sb.x), __fsub_rn(sb.w, sb.y));
            }
            __syncthreads();
            float ax1 = sboxsh[0], ay1 = sboxsh[1], ax2 = sboxsh[2], ay2 = sboxsh[3];
            float area_a = sboxsh[4];
            for (int n = tid; n < NN; n += NT) {
                float4 bbn = bx4[n];
                if (iou_ref(ax1, ay1, ax2, ay2, area_a,
                            bbn.x, bbn.y, bbn.z, bbn.w) > NMS_T)
                    atomicOr(&bm[n >> 5], 1u << (n & 31));
            }
            __syncthreads();
        }
    } else {
        for (int kk = n_acc + tid; kk < MAX_DET; kk += NT) { si[kk] = 0; ss[kk] = neg_inf(); }
    }
}

// ---------------- T: per-image top-300 + gather --------------------------
__global__ __launch_bounds__(NT) void topk_kernel(
    const float* __restrict__ boxes, const float* __restrict__ other,
    const int* __restrict__ sel_idx, const float* __restrict__ sel_score,
    float* __restrict__ out)
{
    const int b = blockIdx.x;
    const int tid = threadIdx.x;
    const int NCAND = NC * MAX_DET;       // 2400
    __shared__ u64 keys[4096];

    for (int m = tid; m < 4096; m += NT) {
        u64 key = 0ull;
        if (m < NCAND) {
            float v = sel_score[b * NCAND + m];
            unsigned u = __float_as_uint(v);
            u ^= (u & 0x80000000u) ? 0xFFFFFFFFu : 0x80000000u;
            key = ((u64)u << 32) | (unsigned)(~(unsigned)m);
        }
        keys[m] = key;
    }
    __syncthreads();

    for (int k = 2; k <= 4096; k <<= 1) {
        for (int j = k >> 1; j > 0; j >>= 1) {
            for (int p = tid; p < 2048; p += NT) {
                int i = 2 * p - (p & (j - 1));
                int ix = i + j;
                bool dir = ((i & k) == 0);
                u64 a = keys[i], bq = keys[ix];
                if ((a < bq) == dir) { keys[i] = bq; keys[ix] = a; }
            }
            __syncthreads();
        }
    }

    const float4* bx4 = (const float4*)(boxes + (size_t)b * NN * 4);
    const float*  ot  = other + (size_t)b * NN * ND;
    float* ob = out;
    float* os = out + NB * MAX_DET * 4;
    float* ol = os + NB * MAX_DET;
    float* oo = ol + NB * MAX_DET;

    for (int k = tid; k < MAX_DET; k += NT) {
        u64 key = keys[k];
        unsigned u = (unsigned)(key >> 32);
        unsigned uo = (u & 0x80000000u) ? (u ^ 0x80000000u) : (u ^ 0xFFFFFFFFu);
        float score = __uint_as_float(uo);
        bool valid = isfinite(score);
        float b0=-1.f,b1=-1.f,b2=-1.f,b3=-1.f,scv=-1.f,lab=-1.f,o0=-1.f,o1=-1.f;
        if (valid) {
            int m = (int)(~(unsigned)key);
            int c = m / MAX_DET, slot = m - c * MAX_DET;
            int n = sel_idx[(b * NC + c) * MAX_DET + slot];
            float4 bb = bx4[n];
            b0 = bb.x; b1 = bb.y; b2 = bb.z; b3 = bb.w;
            scv = score; lab = (float)c;
            o0 = ot[n * ND + 0]; o1 = ot[n * ND + 1];
        }
        int base = b * MAX_DET + k;
        ob[base * 4 + 0] = b0; ob[base * 4 + 1] = b1;
        ob[base * 4 + 2] = b2; ob[base * 4 + 3] = b3;
        os[base] = scv; ol[base] = lab;
        oo[base * 2 + 0] = o0; oo[base * 2 + 1] = o1;
    }
}

extern "C" void kernel_launch(void* const* d_in, const int* in_sizes, int n_in,
                              void* d_out, int out_size, void* d_ws, size_t ws_size,
                              hipStream_t stream) {
    const float* boxes = (const float*)d_in[0];
    const float* cls   = (const float*)d_in[1];
    const float* other = (const float*)d_in[2];
    float* out = (float*)d_out;

    // ws layout: hist[16*8*256] | cnt[128] | cut[128] | tot[128] | cand[128*CAP] u64
    //          | sel_idx[128*300] | sel_score[128*300]
    int* hist_g = (int*)d_ws;
    int* cnt_g  = hist_g + NB * NC * 256;
    int* cut_g  = cnt_g + NB * NC;
    int* tot_g  = cut_g + NB * NC;
    u64* cand   = (u64*)(tot_g + NB * NC);
    int* sel_idx = (int*)(cand + (size_t)NB * NC * CAP);
    float* sel_score = (float*)(sel_idx + NB * NC * MAX_DET);

    const int nzero = NB * NC * 256 + NB * NC;   // hist + cnt (contiguous)
    zero_kernel<<<(nzero + 1023) / 1024, 1024, 0, stream>>>(hist_g, nzero);
    hist_kernel<<<NB * HT, 1024, 0, stream>>>(cls, hist_g);
    cut_kernel<<<1, NB * NC, 0, stream>>>(hist_g, cut_g, tot_g);
    compact_kernel<<<NB * HT, 1024, 0, stream>>>(cls, cut_g, cnt_g, cand);
    nms_kernel<<<NB * NC, NT, 0, stream>>>(boxes, cls, cand, cnt_g, tot_g,
                                           sel_idx, sel_score);
    topk_kernel<<<NB, NT, 0, stream>>>(boxes, other, sel_idx, sel_score, out);
}

// Round 5
// 222.613 us; speedup vs baseline: 3.0774x; 3.0774x over previous
//
#include <hip/hip_runtime.h>
#include <math.h>
#include <stdint.h>

#define NB 16
#define NN 50000
#define NC 8
#define ND 2
#define MAX_DET 300
#define NMS_T 0.5f
#define SCORE_T 0.05f
#define CAP 4096
#define TARGET 2048
#define CHUNK 256
#define NT 512
#define TN 512
#define NTILE ((NN + TN - 1) / TN)   // 98

typedef unsigned long long u64;

__device__ __forceinline__ float neg_inf() { return -__builtin_inff(); }

// IoU in the reference's exact op order; _rn forbids FMA contraction.
__device__ __forceinline__ float iou_ref(float ax1, float ay1, float ax2, float ay2,
                                         float area_a,
                                         float bx1, float by1, float bx2, float by2) {
    float x1 = fmaxf(ax1, bx1), y1 = fmaxf(ay1, by1);
    float x2 = fminf(ax2, bx2), y2 = fminf(ay2, by2);
    float inter = __fmul_rn(fmaxf(__fsub_rn(x2, x1), 0.0f),
                            fmaxf(__fsub_rn(y2, y1), 0.0f));
    float area_b = __fmul_rn(__fsub_rn(bx2, bx1), __fsub_rn(by2, by1));
    float uni = __fsub_rn(__fadd_rn(area_a, area_b), inter);
    return __fdiv_rn(inter, fmaxf(uni, 1e-8f));
}

// ---------------- transpose: cls[B,N,C] -> clsT[B,C,N] --------------------
__global__ __launch_bounds__(512) void transpose_kernel(
    const float* __restrict__ cls, float* __restrict__ clsT)
{
    __shared__ float t[8][TN + 4];            // pad 4: read-side <=2-way (free)
    const int b = blockIdx.x / NTILE, tile = blockIdx.x % NTILE;
    const int n0 = tile * TN;
    const int count = (NN - n0) < TN ? (NN - n0) : TN;
    const float* src = cls + ((size_t)b * NN + n0) * NC;
    for (int i = threadIdx.x; i < count * NC; i += 512) {
        int n = i >> 3, c = i & 7;
        t[c][n] = src[i];
    }
    __syncthreads();
    for (int c = 0; c < NC; ++c)
        for (int i = threadIdx.x; i < count; i += 512)
            clsT[((size_t)b * NC + c) * NN + n0 + i] = t[c][i];
}

// ---------------- N: in-block hist+cut+compact, sort, chunked greedy ------
// STRIDE==1: scores = clsT row (contiguous). STRIDE==NC: raw cls (ws too small).
template<int STRIDE>
__global__ __launch_bounds__(NT) void nms_kernel(
    const float* __restrict__ boxes, const float* __restrict__ scores_base,
    int* __restrict__ sel_idx, float* __restrict__ sel_score)
{
    const int bc = blockIdx.x;
    const int b = bc >> 3, c = bc & 7;
    const int tid = threadIdx.x;
    const float4* bx4 = (const float4*)(boxes + (size_t)b * NN * 4);
    const float* sr = (STRIDE == 1) ? scores_base + (size_t)bc * NN
                                    : scores_base + (size_t)b * NN * NC + c;
    int* si = sel_idx + bc * MAX_DET;
    float* ss = sel_score + bc * MAX_DET;

    __shared__ u64 keys[CAP];                  // 32 KB (aliased as fallback bitmask)
    __shared__ u64 M[4][CHUNK];                // 8 KB
    __shared__ float4 cbox[CHUNK];
    __shared__ float carea[CHUNK];
    __shared__ int   cidx[CHUNK];
    __shared__ float cscore[CHUNK];
    __shared__ unsigned presup[CHUNK];
    __shared__ u64 accmask_s[4];
    __shared__ float4 abox[MAX_DET];
    __shared__ float aarea[MAX_DET];
    __shared__ int hist[256];
    __shared__ int sh_cnt, sh_cut, sh_total;
    __shared__ float rv[NT];
    __shared__ int   ri[NT];
    __shared__ float sboxsh[5];

    // ---- pass 1: histogram ----
    if (tid < 256) hist[tid] = 0;
    if (tid == 0) sh_cnt = 0;
    __syncthreads();
    if (STRIDE == 1) {
        const float4* s4 = (const float4*)sr;
        for (int f = tid; f < NN / 4; f += NT) {
            float4 v = s4[f];
            float vv[4] = {v.x, v.y, v.z, v.w};
            #pragma unroll
            for (int k = 0; k < 4; ++k) {
                float s = vv[k];
                if (s > SCORE_T) {
                    int bn = (int)(s * 256.0f); bn = bn > 255 ? 255 : bn;
                    atomicAdd(&hist[bn], 1);
                }
            }
        }
    } else {
        for (int n = tid; n < NN; n += NT) {
            float s = sr[(size_t)n * STRIDE];
            if (s > SCORE_T) {
                int bn = (int)(s * 256.0f); bn = bn > 255 ? 255 : bn;
                atomicAdd(&hist[bn], 1);
            }
        }
    }
    __syncthreads();
    if (tid == 0) {
        int total = 0;
        for (int i = 0; i < 256; ++i) total += hist[i];
        int suff = 0, cut = 0;
        for (int bn = 255; bn >= 0; --bn) {
            suff += hist[bn];
            if (suff >= TARGET) { cut = bn; break; }
        }
        sh_cut = cut; sh_total = total;
    }
    __syncthreads();
    const int cut = sh_cut;

    // ---- pass 2: compact (LDS atomics only) ----
    if (STRIDE == 1) {
        const float4* s4 = (const float4*)sr;
        for (int f = tid; f < NN / 4; f += NT) {
            float4 v = s4[f];
            float vv[4] = {v.x, v.y, v.z, v.w};
            #pragma unroll
            for (int k = 0; k < 4; ++k) {
                float s = vv[k];
                if (s > SCORE_T) {
                    int bn = (int)(s * 256.0f); bn = bn > 255 ? 255 : bn;
                    if (bn >= cut) {
                        int p = atomicAdd(&sh_cnt, 1);
                        if (p < CAP) {
                            int n = f * 4 + k;
                            unsigned u = __float_as_uint(s);
                            u ^= (u & 0x80000000u) ? 0xFFFFFFFFu : 0x80000000u;
                            keys[p] = ((u64)u << 32) | (unsigned)(~(unsigned)n);
                        }
                    }
                }
            }
        }
    } else {
        for (int n = tid; n < NN; n += NT) {
            float s = sr[(size_t)n * STRIDE];
            if (s > SCORE_T) {
                int bn = (int)(s * 256.0f); bn = bn > 255 ? 255 : bn;
                if (bn >= cut) {
                    int p = atomicAdd(&sh_cnt, 1);
                    if (p < CAP) {
                        unsigned u = __float_as_uint(s);
                        u ^= (u & 0x80000000u) ? 0xFFFFFFFFu : 0x80000000u;
                        keys[p] = ((u64)u << 32) | (unsigned)(~(unsigned)n);
                    }
                }
            }
        }
    }
    __syncthreads();
    const int cnt = sh_cnt, total = sh_total;
    const bool full_fb = (cnt > CAP);
    const int inSet = cnt < CAP ? cnt : CAP;
    for (int i = inSet + tid; i < CAP; i += NT) keys[i] = 0ull;  // pad sorts last
    __syncthreads();

    int n_acc = 0;
    if (!full_fb) {
        // bitonic sort descending: (score desc, idx asc)
        for (int k = 2; k <= CAP; k <<= 1) {
            for (int j = k >> 1; j > 0; j >>= 1) {
                for (int p = tid; p < CAP / 2; p += NT) {
                    int i = 2 * p - (p & (j - 1));
                    int ix = i + j;
                    bool dir = ((i & k) == 0);
                    u64 a = keys[i], bq = keys[ix];
                    if ((a < bq) == dir) { keys[i] = bq; keys[ix] = a; }
                }
                __syncthreads();
            }
        }

        // chunked matrix greedy accept
        int base = 0;
        while (n_acc < MAX_DET && base < inSet) {
            int m = inSet - base; if (m > CHUNK) m = CHUNK;

            if (tid < CHUNK) {
                if (tid < m) {
                    u64 key = keys[base + tid];
                    int idx = (int)(~(unsigned)key);
                    unsigned u = (unsigned)(key >> 32);
                    unsigned uo = (u & 0x80000000u) ? (u ^ 0x80000000u) : (~u);
                    float4 bb = bx4[idx];
                    cbox[tid] = bb;
                    carea[tid] = __fmul_rn(__fsub_rn(bb.z, bb.x), __fsub_rn(bb.w, bb.y));
                    cidx[tid] = idx; cscore[tid] = __uint_as_float(uo);
                    presup[tid] = 0u;
                } else presup[tid] = 1u;
            }
            __syncthreads();

            {
                int i = tid & (CHUNK - 1);
                int half = tid >> 8;               // 0 or 1
                if (i < m) {
                    float4 B = cbox[i];
                    unsigned p = 0;
                    for (int t = half; t < n_acc; t += 2) {
                        float4 A = abox[t];
                        if (iou_ref(A.x, A.y, A.z, A.w, aarea[t],
                                    B.x, B.y, B.z, B.w) > NMS_T) { p = 1; break; }
                    }
                    if (p) atomicOr(&presup[i], 1u);
                    for (int w = half * 2; w < half * 2 + 2; ++w) {
                        u64 bits = 0;
                        int j0 = w * 64;
                        for (int jj = 0; jj < 64; ++jj) {
                            int j = j0 + jj;
                            if (j < m && j != i) {
                                float4 A = cbox[j];
                                if (iou_ref(A.x, A.y, A.z, A.w, carea[j],
                                            B.x, B.y, B.z, B.w) > NMS_T)
                                    bits |= 1ull << jj;
                            }
                        }
                        M[w][i] = bits;
                    }
                }
            }
            __syncthreads();

            if (tid < 64) {
                u64 a0 = 0, a1 = 0, a2 = 0, a3 = 0;
                int ngroups = (m + 63) >> 6;
                for (int g = 0; g < ngroups; ++g) {
                    int i = g * 64 + tid;
                    unsigned pe = 1; u64 mg = 0;
                    if (i < m) {
                        pe = presup[i];
                        mg = M[g][i];
                        u64 fold = 0;
                        if (g > 0) fold |= M[0][i] & a0;
                        if (g > 1) fold |= M[1][i] & a1;
                        if (g > 2) fold |= M[2][i] & a2;
                        if (fold) pe = 1;
                    }
                    u64 accw = 0;
                    for (int l = 0; l < 64; ++l) {
                        u64 mgl = __shfl(mg, l, 64);
                        unsigned pel = __shfl(pe, l, 64);
                        if (!pel && (mgl & accw) == 0ull) accw |= 1ull << l;
                    }
                    if (g == 0) a0 = accw; else if (g == 1) a1 = accw;
                    else if (g == 2) a2 = accw; else a3 = accw;
                }
                if (tid == 0) {
                    accmask_s[0] = a0; accmask_s[1] = a1;
                    accmask_s[2] = a2; accmask_s[3] = a3;
                }
            }
            __syncthreads();

            u64 a0 = accmask_s[0], a1 = accmask_s[1], a2 = accmask_s[2], a3 = accmask_s[3];
            int add = __popcll(a0) + __popcll(a1) + __popcll(a2) + __popcll(a3);
            if (tid < m) {
                int g = tid >> 6, o = tid & 63;
                u64 aw = (g == 0) ? a0 : (g == 1) ? a1 : (g == 2) ? a2 : a3;
                if ((aw >> o) & 1ull) {
                    int rank = 0;
                    if (g > 0) rank += __popcll(a0);
                    if (g > 1) rank += __popcll(a1);
                    if (g > 2) rank += __popcll(a2);
                    rank += __popcll(aw & ((1ull << o) - 1ull));
                    int pos = n_acc + rank;
                    if (pos < MAX_DET) {
                        abox[pos] = cbox[tid]; aarea[pos] = carea[tid];
                        si[pos] = cidx[tid]; ss[pos] = cscore[tid];
                    }
                }
            }
            n_acc += add; if (n_acc > MAX_DET) n_acc = MAX_DET;
            base += m;
            __syncthreads();
        }
    }

    const bool part_fb = (!full_fb) && (n_acc < MAX_DET) && (total > inSet);

    if (full_fb || part_fb) {
        // exact fallback; suppression bitmask aliases keys[]
        unsigned* bm = (unsigned*)keys;
        const int BMW = (NN + 31) / 32;
        for (int i = tid; i < BMW; i += NT) bm[i] = 0u;
        __syncthreads();
        if (full_fb) {
            n_acc = 0;
        } else {
            for (int n = tid; n < NN; n += NT) {
                float4 bbn = bx4[n];
                int s = 0;
                for (int t = 0; t < n_acc; ++t) {
                    float4 A = abox[t];
                    if (iou_ref(A.x, A.y, A.z, A.w, aarea[t],
                                bbn.x, bbn.y, bbn.z, bbn.w) > NMS_T) s = 1;
                }
                if (s) atomicOr(&bm[n >> 5], 1u << (n & 31));
            }
        }
        __syncthreads();

        for (int k = n_acc; k < MAX_DET; ++k) {
            float bv = neg_inf(); int bi = 0x7fffffff;
            for (int n = tid; n < NN; n += NT) {
                if (!((bm[n >> 5] >> (n & 31)) & 1u)) {
                    float v = sr[(size_t)n * STRIDE];
                    if (v > SCORE_T && v > bv) { bv = v; bi = n; }
                }
            }
            rv[tid] = bv; ri[tid] = bi;
            __syncthreads();
            for (int s = NT / 2; s > 0; s >>= 1) {
                if (tid < s) {
                    float ov = rv[tid + s]; int oi = ri[tid + s];
                    if (ov > rv[tid] || (ov == rv[tid] && oi < ri[tid])) { rv[tid] = ov; ri[tid] = oi; }
                }
                __syncthreads();
            }
            float mval = rv[0]; int midx = ri[0];
            if (mval == neg_inf()) {
                for (int kk = k + tid; kk < MAX_DET; kk += NT) { si[kk] = 0; ss[kk] = neg_inf(); }
                break;
            }
            if (tid == 0) {
                si[k] = midx; ss[k] = mval;
                float4 sb = bx4[midx];
                sboxsh[0] = sb.x; sboxsh[1] = sb.y; sboxsh[2] = sb.z; sboxsh[3] = sb.w;
                sboxsh[4] = __fmul_rn(__fsub_rn(sb.z, sb.x), __fsub_rn(sb.w, sb.y));
            }
            __syncthreads();
            float ax1 = sboxsh[0], ay1 = sboxsh[1], ax2 = sboxsh[2], ay2 = sboxsh[3];
            float area_a = sboxsh[4];
            for (int n = tid; n < NN; n += NT) {
                float4 bbn = bx4[n];
                if (iou_ref(ax1, ay1, ax2, ay2, area_a,
                            bbn.x, bbn.y, bbn.z, bbn.w) > NMS_T)
                    atomicOr(&bm[n >> 5], 1u << (n & 31));
            }
            __syncthreads();
        }
    } else {
        for (int kk = n_acc + tid; kk < MAX_DET; kk += NT) { si[kk] = 0; ss[kk] = neg_inf(); }
    }
}

// ---------------- T: per-image top-300 + gather --------------------------
__global__ __launch_bounds__(NT) void topk_kernel(
    const float* __restrict__ boxes, const float* __restrict__ other,
    const int* __restrict__ sel_idx, const float* __restrict__ sel_score,
    float* __restrict__ out)
{
    const int b = blockIdx.x;
    const int tid = threadIdx.x;
    const int NCAND = NC * MAX_DET;       // 2400
    __shared__ u64 keys[4096];

    for (int m = tid; m < 4096; m += NT) {
        u64 key = 0ull;
        if (m < NCAND) {
            float v = sel_score[b * NCAND + m];
            unsigned u = __float_as_uint(v);
            u ^= (u & 0x80000000u) ? 0xFFFFFFFFu : 0x80000000u;
            key = ((u64)u << 32) | (unsigned)(~(unsigned)m);
        }
        keys[m] = key;
    }
    __syncthreads();

    for (int k = 2; k <= 4096; k <<= 1) {
        for (int j = k >> 1; j > 0; j >>= 1) {
            for (int p = tid; p < 2048; p += NT) {
                int i = 2 * p - (p & (j - 1));
                int ix = i + j;
                bool dir = ((i & k) == 0);
                u64 a = keys[i], bq = keys[ix];
                if ((a < bq) == dir) { keys[i] = bq; keys[ix] = a; }
            }
            __syncthreads();
        }
    }

    const float4* bx4 = (const float4*)(boxes + (size_t)b * NN * 4);
    const float*  ot  = other + (size_t)b * NN * ND;
    float* ob = out;
    float* os = out + NB * MAX_DET * 4;
    float* ol = os + NB * MAX_DET;
    float* oo = ol + NB * MAX_DET;

    for (int k = tid; k < MAX_DET; k += NT) {
        u64 key = keys[k];
        unsigned u = (unsigned)(key >> 32);
        unsigned uo = (u & 0x80000000u) ? (u ^ 0x80000000u) : (u ^ 0xFFFFFFFFu);
        float score = __uint_as_float(uo);
        bool valid = isfinite(score);
        float b0=-1.f,b1=-1.f,b2=-1.f,b3=-1.f,scv=-1.f,lab=-1.f,o0=-1.f,o1=-1.f;
        if (valid) {
            int m = (int)(~(unsigned)key);
            int c = m / MAX_DET, slot = m - c * MAX_DET;
            int n = sel_idx[(b * NC + c) * MAX_DET + slot];
            float4 bb = bx4[n];
            b0 = bb.x; b1 = bb.y; b2 = bb.z; b3 = bb.w;
            scv = score; lab = (float)c;
            o0 = ot[n * ND + 0]; o1 = ot[n * ND + 1];
        }
        int base = b * MAX_DET + k;
        ob[base * 4 + 0] = b0; ob[base * 4 + 1] = b1;
        ob[base * 4 + 2] = b2; ob[base * 4 + 3] = b3;
        os[base] = scv; ol[base] = lab;
        oo[base * 2 + 0] = o0; oo[base * 2 + 1] = o1;
    }
}

extern "C" void kernel_launch(void* const* d_in, const int* in_sizes, int n_in,
                              void* d_out, int out_size, void* d_ws, size_t ws_size,
                              hipStream_t stream) {
    const float* boxes = (const float*)d_in[0];
    const float* cls   = (const float*)d_in[1];
    const float* other = (const float*)d_in[2];
    float* out = (float*)d_out;

    const size_t clsT_elems = (size_t)NB * NC * NN;
    const size_t sel_elems  = (size_t)NB * NC * MAX_DET;
    const size_t need_fast  = (clsT_elems + 2 * sel_elems) * 4;

    if (ws_size >= need_fast) {
        float* clsT = (float*)d_ws;
        int* sel_idx = (int*)(clsT + clsT_elems);
        float* sel_score = (float*)(sel_idx + sel_elems);
        transpose_kernel<<<NB * NTILE, 512, 0, stream>>>(cls, clsT);
        nms_kernel<1><<<NB * NC, NT, 0, stream>>>(boxes, clsT, sel_idx, sel_score);
        topk_kernel<<<NB, NT, 0, stream>>>(boxes, other, sel_idx, sel_score, out);
    } else {
        int* sel_idx = (int*)d_ws;
        float* sel_score = (float*)(sel_idx + sel_elems);
        nms_kernel<NC><<<NB * NC, NT, 0, stream>>>(boxes, cls, sel_idx, sel_score);
        topk_kernel<<<NB, NT, 0, stream>>>(boxes, other, sel_idx, sel_score, out);
    }
}

// Round 6
// 140.110 us; speedup vs baseline: 4.8894x; 1.5888x over previous
//
#include <hip/hip_runtime.h>
#include <math.h>
#include <stdint.h>

#define NB 16
#define NN 50000
#define NC 8
#define ND 2
#define MAX_DET 300
#define NMS_T 0.5f
#define SCORE_T 0.05f
#define CAP 1024          // pow2; holds cnt in [TARGET, TARGET+maxbin] w/ margin
#define TARGET 512
#define CHUNK 128
#define NT 512
#define TN 512
#define NTILE ((NN + TN - 1) / TN)   // 98

typedef unsigned long long u64;

__device__ __forceinline__ float neg_inf() { return -__builtin_inff(); }

// IoU in the reference's exact op order; _rn forbids FMA contraction.
__device__ __forceinline__ float iou_ref(float ax1, float ay1, float ax2, float ay2,
                                         float area_a,
                                         float bx1, float by1, float bx2, float by2) {
    float x1 = fmaxf(ax1, bx1), y1 = fmaxf(ay1, by1);
    float x2 = fminf(ax2, bx2), y2 = fminf(ay2, by2);
    float inter = __fmul_rn(fmaxf(__fsub_rn(x2, x1), 0.0f),
                            fmaxf(__fsub_rn(y2, y1), 0.0f));
    float area_b = __fmul_rn(__fsub_rn(bx2, bx1), __fsub_rn(by2, by1));
    float uni = __fsub_rn(__fadd_rn(area_a, area_b), inter);
    return __fdiv_rn(inter, fmaxf(uni, 1e-8f));
}

// ---------------- transpose: cls[B,N,C] -> clsT[B,C,N] --------------------
__global__ __launch_bounds__(512) void transpose_kernel(
    const float* __restrict__ cls, float* __restrict__ clsT)
{
    __shared__ float t[8][TN + 4];
    const int b = blockIdx.x / NTILE, tile = blockIdx.x % NTILE;
    const int n0 = tile * TN;
    const int count = (NN - n0) < TN ? (NN - n0) : TN;
    const float* src = cls + ((size_t)b * NN + n0) * NC;
    for (int i = threadIdx.x; i < count * NC; i += 512) {
        int n = i >> 3, c = i & 7;
        t[c][n] = src[i];
    }
    __syncthreads();
    for (int c = 0; c < NC; ++c)
        for (int i = threadIdx.x; i < count; i += 512)
            clsT[((size_t)b * NC + c) * NN + n0 + i] = t[c][i];
}

// ---------------- N: hist+cut+compact, sort, chunked greedy ---------------
template<int STRIDE>
__global__ __launch_bounds__(NT) void nms_kernel(
    const float* __restrict__ boxes, const float* __restrict__ scores_base,
    int* __restrict__ sel_idx, float* __restrict__ sel_score)
{
    const int bc = blockIdx.x;
    const int b = bc >> 3, c = bc & 7;
    const int tid = threadIdx.x;
    const float4* bx4 = (const float4*)(boxes + (size_t)b * NN * 4);
    const float* sr = (STRIDE == 1) ? scores_base + (size_t)bc * NN
                                    : scores_base + (size_t)b * NN * NC + c;
    int* si = sel_idx + bc * MAX_DET;
    float* ss = sel_score + bc * MAX_DET;

    __shared__ u64 keys[CAP];                  // 8 KB (aliased as fallback bitmask)
    __shared__ unsigned M32[4][CHUNK];         // 2 KB: M32[q][i] = pairs j in [32q,32q+32)
    __shared__ float4 cbox[CHUNK];
    __shared__ float carea[CHUNK];
    __shared__ int   cidx[CHUNK];
    __shared__ float cscore[CHUNK];
    __shared__ unsigned presup[CHUNK];
    __shared__ u64 accmask_s[2];
    __shared__ float4 abox[MAX_DET];
    __shared__ float aarea[MAX_DET];
    __shared__ int hist[256];
    __shared__ int sh_cnt, sh_cut, sh_total;
    __shared__ float rv[NT];
    __shared__ int   ri[NT];
    __shared__ float sboxsh[5];

    // ---- pass 1: histogram ----
    if (tid < 256) hist[tid] = 0;
    if (tid == 0) sh_cnt = 0;
    __syncthreads();
    if (STRIDE == 1) {
        const float4* s4 = (const float4*)sr;
        for (int f = tid; f < NN / 4; f += NT) {
            float4 v = s4[f];
            float vv[4] = {v.x, v.y, v.z, v.w};
            #pragma unroll
            for (int k = 0; k < 4; ++k) {
                float s = vv[k];
                if (s > SCORE_T) {
                    int bn = (int)(s * 256.0f); bn = bn > 255 ? 255 : bn;
                    atomicAdd(&hist[bn], 1);
                }
            }
        }
    } else {
        for (int n = tid; n < NN; n += NT) {
            float s = sr[(size_t)n * STRIDE];
            if (s > SCORE_T) {
                int bn = (int)(s * 256.0f); bn = bn > 255 ? 255 : bn;
                atomicAdd(&hist[bn], 1);
            }
        }
    }
    __syncthreads();
    if (tid == 0) {
        int total = 0;
        for (int i = 0; i < 256; ++i) total += hist[i];
        int suff = 0, cut = 0;
        for (int bn = 255; bn >= 0; --bn) {
            suff += hist[bn];
            if (suff >= TARGET) { cut = bn; break; }
        }
        sh_cut = cut; sh_total = total;
    }
    __syncthreads();
    const int cut = sh_cut;

    // ---- pass 2: compact (LDS atomics only) ----
    if (STRIDE == 1) {
        const float4* s4 = (const float4*)sr;
        for (int f = tid; f < NN / 4; f += NT) {
            float4 v = s4[f];
            float vv[4] = {v.x, v.y, v.z, v.w};
            #pragma unroll
            for (int k = 0; k < 4; ++k) {
                float s = vv[k];
                if (s > SCORE_T) {
                    int bn = (int)(s * 256.0f); bn = bn > 255 ? 255 : bn;
                    if (bn >= cut) {
                        int p = atomicAdd(&sh_cnt, 1);
                        if (p < CAP) {
                            int n = f * 4 + k;
                            unsigned u = __float_as_uint(s);
                            u ^= (u & 0x80000000u) ? 0xFFFFFFFFu : 0x80000000u;
                            keys[p] = ((u64)u << 32) | (unsigned)(~(unsigned)n);
                        }
                    }
                }
            }
        }
    } else {
        for (int n = tid; n < NN; n += NT) {
            float s = sr[(size_t)n * STRIDE];
            if (s > SCORE_T) {
                int bn = (int)(s * 256.0f); bn = bn > 255 ? 255 : bn;
                if (bn >= cut) {
                    int p = atomicAdd(&sh_cnt, 1);
                    if (p < CAP) {
                        unsigned u = __float_as_uint(s);
                        u ^= (u & 0x80000000u) ? 0xFFFFFFFFu : 0x80000000u;
                        keys[p] = ((u64)u << 32) | (unsigned)(~(unsigned)n);
                    }
                }
            }
        }
    }
    __syncthreads();
    const int cnt = sh_cnt, total = sh_total;
    const bool full_fb = (cnt > CAP);
    const int inSet = cnt < CAP ? cnt : CAP;
    for (int i = inSet + tid; i < CAP; i += NT) keys[i] = 0ull;
    __syncthreads();

    int n_acc = 0;
    if (!full_fb) {
        // bitonic sort CAP=1024 descending; 512 thr -> exactly 1 CE per pass
        for (int k = 2; k <= CAP; k <<= 1) {
            for (int j = k >> 1; j > 0; j >>= 1) {
                int p = tid;
                int i = 2 * p - (p & (j - 1));
                int ix = i + j;
                bool dir = ((i & k) == 0);
                u64 a = keys[i], bq = keys[ix];
                if ((a < bq) == dir) { keys[i] = bq; keys[ix] = a; }
                __syncthreads();
            }
        }

        // chunked matrix greedy accept (CHUNK=128, 4 threads per candidate)
        int base = 0;
        while (n_acc < MAX_DET && base < inSet) {
            int m = inSet - base; if (m > CHUNK) m = CHUNK;

            if (tid < CHUNK) {
                if (tid < m) {
                    u64 key = keys[base + tid];
                    int idx = (int)(~(unsigned)key);
                    unsigned u = (unsigned)(key >> 32);
                    unsigned uo = (u & 0x80000000u) ? (u ^ 0x80000000u) : (~u);
                    float4 bb = bx4[idx];
                    cbox[tid] = bb;
                    carea[tid] = __fmul_rn(__fsub_rn(bb.z, bb.x), __fsub_rn(bb.w, bb.y));
                    cidx[tid] = idx; cscore[tid] = __uint_as_float(uo);
                    presup[tid] = 0u;
                } else presup[tid] = 1u;
            }
            __syncthreads();

            {
                int i = tid & (CHUNK - 1);
                int q = tid >> 7;                  // 0..3
                if (i < m) {
                    float4 B = cbox[i];
                    unsigned p = 0;
                    for (int t = q; t < n_acc; t += 4) {
                        float4 A = abox[t];
                        if (iou_ref(A.x, A.y, A.z, A.w, aarea[t],
                                    B.x, B.y, B.z, B.w) > NMS_T) { p = 1; break; }
                    }
                    if (p) atomicOr(&presup[i], 1u);
                    unsigned bits = 0;
                    int j0 = q * 32;
                    for (int jj = 0; jj < 32; ++jj) {
                        int j = j0 + jj;
                        if (j < m && j != i) {
                            float4 A = cbox[j];
                            if (iou_ref(A.x, A.y, A.z, A.w, carea[j],
                                        B.x, B.y, B.z, B.w) > NMS_T)
                                bits |= 1u << jj;
                        }
                    }
                    M32[q][i] = bits;
                }
            }
            __syncthreads();

            if (tid < 64) {
                u64 a0 = 0, a1 = 0;
                int ngroups = (m + 63) >> 6;       // 1 or 2
                for (int g = 0; g < ngroups; ++g) {
                    int i = g * 64 + tid;
                    unsigned pe = 1; u64 mg = 0;
                    if (i < m) {
                        pe = presup[i];
                        mg = (u64)M32[2 * g][i] | ((u64)M32[2 * g + 1][i] << 32);
                        if (g > 0) {
                            u64 w0 = (u64)M32[0][i] | ((u64)M32[1][i] << 32);
                            if (w0 & a0) pe = 1;
                        }
                    }
                    u64 accw = 0;
                    for (int l = 0; l < 64; ++l) {
                        u64 mgl = __shfl(mg, l, 64);
                        unsigned pel = __shfl(pe, l, 64);
                        if (!pel && (mgl & accw) == 0ull) accw |= 1ull << l;
                    }
                    if (g == 0) a0 = accw; else a1 = accw;
                }
                if (tid == 0) { accmask_s[0] = a0; accmask_s[1] = a1; }
            }
            __syncthreads();

            u64 a0 = accmask_s[0], a1 = accmask_s[1];
            int add = __popcll(a0) + __popcll(a1);
            if (tid < m) {
                int g = tid >> 6, o = tid & 63;
                u64 aw = (g == 0) ? a0 : a1;
                if ((aw >> o) & 1ull) {
                    int rank = (g > 0) ? __popcll(a0) : 0;
                    rank += __popcll(aw & ((1ull << o) - 1ull));
                    int pos = n_acc + rank;
                    if (pos < MAX_DET) {
                        abox[pos] = cbox[tid]; aarea[pos] = carea[tid];
                        si[pos] = cidx[tid]; ss[pos] = cscore[tid];
                    }
                }
            }
            n_acc += add; if (n_acc > MAX_DET) n_acc = MAX_DET;
            base += m;
            __syncthreads();
        }
    }

    const bool part_fb = (!full_fb) && (n_acc < MAX_DET) && (total > inSet);

    if (full_fb || part_fb) {
        // exact fallback; suppression bitmask aliases keys[] (6.25 KB <= 8 KB)
        unsigned* bm = (unsigned*)keys;
        const int BMW = (NN + 31) / 32;
        for (int i = tid; i < BMW; i += NT) bm[i] = 0u;
        __syncthreads();
        if (full_fb) {
            n_acc = 0;
        } else {
            for (int n = tid; n < NN; n += NT) {
                float4 bbn = bx4[n];
                int s = 0;
                for (int t = 0; t < n_acc; ++t) {
                    float4 A = abox[t];
                    if (iou_ref(A.x, A.y, A.z, A.w, aarea[t],
                                bbn.x, bbn.y, bbn.z, bbn.w) > NMS_T) s = 1;
                }
                if (s) atomicOr(&bm[n >> 5], 1u << (n & 31));
            }
        }
        __syncthreads();

        for (int k = n_acc; k < MAX_DET; ++k) {
            float bv = neg_inf(); int bi = 0x7fffffff;
            for (int n = tid; n < NN; n += NT) {
                if (!((bm[n >> 5] >> (n & 31)) & 1u)) {
                    float v = sr[(size_t)n * STRIDE];
                    if (v > SCORE_T && v > bv) { bv = v; bi = n; }
                }
            }
            rv[tid] = bv; ri[tid] = bi;
            __syncthreads();
            for (int s = NT / 2; s > 0; s >>= 1) {
                if (tid < s) {
                    float ov = rv[tid + s]; int oi = ri[tid + s];
                    if (ov > rv[tid] || (ov == rv[tid] && oi < ri[tid])) { rv[tid] = ov; ri[tid] = oi; }
                }
                __syncthreads();
            }
            float mval = rv[0]; int midx = ri[0];
            if (mval == neg_inf()) {
                for (int kk = k + tid; kk < MAX_DET; kk += NT) { si[kk] = 0; ss[kk] = neg_inf(); }
                break;
            }
            if (tid == 0) {
                si[k] = midx; ss[k] = mval;
                float4 sb = bx4[midx];
                sboxsh[0] = sb.x; sboxsh[1] = sb.y; sboxsh[2] = sb.z; sboxsh[3] = sb.w;
                sboxsh[4] = __fmul_rn(__fsub_rn(sb.z, sb.x), __fsub_rn(sb.w, sb.y));
            }
            __syncthreads();
            float ax1 = sboxsh[0], ay1 = sboxsh[1], ax2 = sboxsh[2], ay2 = sboxsh[3];
            float area_a = sboxsh[4];
            for (int n = tid; n < NN; n += NT) {
                float4 bbn = bx4[n];
                if (iou_ref(ax1, ay1, ax2, ay2, area_a,
                            bbn.x, bbn.y, bbn.z, bbn.w) > NMS_T)
                    atomicOr(&bm[n >> 5], 1u << (n & 31));
            }
            __syncthreads();
        }
    } else {
        for (int kk = n_acc + tid; kk < MAX_DET; kk += NT) { si[kk] = 0; ss[kk] = neg_inf(); }
    }
}

// ---------------- T: per-image top-300 + gather (1024 thr) ----------------
__global__ __launch_bounds__(1024) void topk_kernel(
    const float* __restrict__ boxes, const float* __restrict__ other,
    const int* __restrict__ sel_idx, const float* __restrict__ sel_score,
    float* __restrict__ out)
{
    const int b = blockIdx.x;
    const int tid = threadIdx.x;
    const int NCAND = NC * MAX_DET;       // 2400
    __shared__ u64 keys[4096];

    for (int m = tid; m < 4096; m += 1024) {
        u64 key = 0ull;
        if (m < NCAND) {
            float v = sel_score[b * NCAND + m];
            unsigned u = __float_as_uint(v);
            u ^= (u & 0x80000000u) ? 0xFFFFFFFFu : 0x80000000u;
            key = ((u64)u << 32) | (unsigned)(~(unsigned)m);
        }
        keys[m] = key;
    }
    __syncthreads();

    for (int k = 2; k <= 4096; k <<= 1) {
        for (int j = k >> 1; j > 0; j >>= 1) {
            for (int p = tid; p < 2048; p += 1024) {
                int i = 2 * p - (p & (j - 1));
                int ix = i + j;
                bool dir = ((i & k) == 0);
                u64 a = keys[i], bq = keys[ix];
                if ((a < bq) == dir) { keys[i] = bq; keys[ix] = a; }
            }
            __syncthreads();
        }
    }

    const float4* bx4 = (const float4*)(boxes + (size_t)b * NN * 4);
    const float*  ot  = other + (size_t)b * NN * ND;
    float* ob = out;
    float* os = out + NB * MAX_DET * 4;
    float* ol = os + NB * MAX_DET;
    float* oo = ol + NB * MAX_DET;

    for (int k = tid; k < MAX_DET; k += 1024) {
        u64 key = keys[k];
        unsigned u = (unsigned)(key >> 32);
        unsigned uo = (u & 0x80000000u) ? (u ^ 0x80000000u) : (u ^ 0xFFFFFFFFu);
        float score = __uint_as_float(uo);
        bool valid = isfinite(score);
        float b0=-1.f,b1=-1.f,b2=-1.f,b3=-1.f,scv=-1.f,lab=-1.f,o0=-1.f,o1=-1.f;
        if (valid) {
            int m = (int)(~(unsigned)key);
            int c = m / MAX_DET, slot = m - c * MAX_DET;
            int n = sel_idx[(b * NC + c) * MAX_DET + slot];
            float4 bb = bx4[n];
            b0 = bb.x; b1 = bb.y; b2 = bb.z; b3 = bb.w;
            scv = score; lab = (float)c;
            o0 = ot[n * ND + 0]; o1 = ot[n * ND + 1];
        }
        int base = b * MAX_DET + k;
        ob[base * 4 + 0] = b0; ob[base * 4 + 1] = b1;
        ob[base * 4 + 2] = b2; ob[base * 4 + 3] = b3;
        os[base] = scv; ol[base] = lab;
        oo[base * 2 + 0] = o0; oo[base * 2 + 1] = o1;
    }
}

extern "C" void kernel_launch(void* const* d_in, const int* in_sizes, int n_in,
                              void* d_out, int out_size, void* d_ws, size_t ws_size,
                              hipStream_t stream) {
    const float* boxes = (const float*)d_in[0];
    const float* cls   = (const float*)d_in[1];
    const float* other = (const float*)d_in[2];
    float* out = (float*)d_out;

    const size_t clsT_elems = (size_t)NB * NC * NN;
    const size_t sel_elems  = (size_t)NB * NC * MAX_DET;
    const size_t need_fast  = (clsT_elems + 2 * sel_elems) * 4;

    if (ws_size >= need_fast) {
        float* clsT = (float*)d_ws;
        int* sel_idx = (int*)(clsT + clsT_elems);
        float* sel_score = (float*)(sel_idx + sel_elems);
        transpose_kernel<<<NB * NTILE, 512, 0, stream>>>(cls, clsT);
        nms_kernel<1><<<NB * NC, NT, 0, stream>>>(boxes, clsT, sel_idx, sel_score);
        topk_kernel<<<NB, 1024, 0, stream>>>(boxes, other, sel_idx, sel_score, out);
    } else {
        int* sel_idx = (int*)d_ws;
        float* sel_score = (float*)(sel_idx + sel_elems);
        nms_kernel<NC><<<NB * NC, NT, 0, stream>>>(boxes, cls, sel_idx, sel_score);
        topk_kernel<<<NB, 1024, 0, stream>>>(boxes, other, sel_idx, sel_score, out);
    }
}

// Round 7
// 94.044 us; speedup vs baseline: 7.2844x; 1.4898x over previous
//
#include <hip/hip_runtime.h>
#include <math.h>
#include <stdint.h>

#define NB 16
#define NN 50000
#define NC 8
#define ND 2
#define MAX_DET 300
#define NMS_T 0.5f
#define SCORE_T 0.05f
#define CAP 1024
#define CUTBIN 252        // s >= 252/256 = 0.984375 ; E[cnt]=781, CAP=+8.7 sigma
#define LBUF 128
#define CHUNK 128
#define NT 512
#define NPI (NN * NC)     // 400000 floats per image
#define CBLK 16           // compact blocks per image
#define F4PB (NPI / 4 / CBLK)  // 6250 float4 per compact block

typedef unsigned long long u64;

__device__ __forceinline__ float neg_inf() { return -__builtin_inff(); }

// IoU in the reference's exact op order; _rn forbids FMA contraction.
__device__ __forceinline__ float iou_ref(float ax1, float ay1, float ax2, float ay2,
                                         float area_a,
                                         float bx1, float by1, float bx2, float by2) {
    float x1 = fmaxf(ax1, bx1), y1 = fmaxf(ay1, by1);
    float x2 = fminf(ax2, bx2), y2 = fminf(ay2, by2);
    float inter = __fmul_rn(fmaxf(__fsub_rn(x2, x1), 0.0f),
                            fmaxf(__fsub_rn(y2, y1), 0.0f));
    float area_b = __fmul_rn(__fsub_rn(bx2, bx1), __fsub_rn(by2, by1));
    float uni = __fsub_rn(__fadd_rn(area_a, area_b), inter);
    return __fdiv_rn(inter, fmaxf(uni, 1e-8f));
}

__device__ __forceinline__ u64 score_key(float s, int n) {
    unsigned u = __float_as_uint(s);
    u ^= (u & 0x80000000u) ? 0xFFFFFFFFu : 0x80000000u;
    return ((u64)u << 32) | (unsigned)(~(unsigned)n);
}

// ---------------- Z: zero counters ---------------------------------------
__global__ void zero_kernel(int* __restrict__ p) {
    p[threadIdx.x] = 0;   // 256: cnt_g[128] + tot_g[128]
}

// ---------------- C: coalesced fixed-threshold compaction ----------------
__global__ __launch_bounds__(1024) void compact_kernel(
    const float* __restrict__ cls, int* __restrict__ cnt_g,
    int* __restrict__ tot_g, u64* __restrict__ cand)
{
    const int b = blockIdx.x >> 4, t16 = blockIdx.x & 15;
    const int tid = threadIdx.x;
    __shared__ u64 buf[8][LBUF];
    __shared__ int lcnt[8], ltot[8], gbase[8];
    if (tid < 8) { lcnt[tid] = 0; ltot[tid] = 0; }
    __syncthreads();

    const float4* c4 = (const float4*)(cls + (size_t)b * NPI);
    const int f0 = t16 * F4PB, fend = f0 + F4PB;   // f0 even always
    unsigned te[4] = {0,0,0,0}, to[4] = {0,0,0,0}; // lane0 accumulators
    const u64 EVEN = 0x5555555555555555ull;

    for (int f = f0 + tid; f < fend; f += 1024) {
        float4 v = c4[f];
        int cb = (f & 1) * 4;
        int n = f >> 1;
        float vv[4] = {v.x, v.y, v.z, v.w};
        #pragma unroll
        for (int k = 0; k < 4; ++k) {
            float s = vv[k];
            if (s > SCORE_T) {
                int bn = (int)(s * 256.0f); if (bn > 255) bn = 255;
                if (bn >= CUTBIN) {
                    int c = cb + k;
                    int pos = atomicAdd(&lcnt[c], 1);
                    u64 key = score_key(s, n);
                    if (pos < LBUF) buf[c][pos] = key;
                    else {   // rare overflow: exact via direct global append
                        int gp = atomicAdd(&cnt_g[b * 8 + c], 1);
                        if (gp < CAP) cand[(size_t)(b * 8 + c) * CAP + gp] = key;
                    }
                }
            }
            // total(s > SCORE_T) per class via ballot; even lanes = even f = classes 0-3
            u64 bal = __ballot(s > SCORE_T);
            if ((tid & 63) == 0) {
                te[k] += (unsigned)__popcll(bal & EVEN);
                to[k] += (unsigned)__popcll(bal & ~EVEN);
            }
        }
    }
    if ((tid & 63) == 0) {
        #pragma unroll
        for (int k = 0; k < 4; ++k) {
            atomicAdd(&ltot[k], (int)te[k]);
            atomicAdd(&ltot[4 + k], (int)to[k]);
        }
    }
    __syncthreads();
    if (tid < 8) {
        int m = lcnt[tid]; if (m > LBUF) m = LBUF;
        gbase[tid] = atomicAdd(&cnt_g[b * 8 + tid], m);
        atomicAdd(&tot_g[b * 8 + tid], ltot[tid]);
    }
    __syncthreads();
    for (int c = 0; c < 8; ++c) {
        int m = lcnt[c]; if (m > LBUF) m = LBUF;
        int gb = gbase[c];
        for (int i = tid; i < m; i += 1024) {
            int gp = gb + i;
            if (gp < CAP) cand[(size_t)(b * 8 + c) * CAP + gp] = buf[c][i];
        }
    }
}

// ---------------- N: sort + chunked greedy NMS ----------------------------
__global__ __launch_bounds__(NT) void nms_kernel(
    const float* __restrict__ boxes, const float* __restrict__ cls,
    const u64* __restrict__ cand, const int* __restrict__ cnt_g,
    const int* __restrict__ tot_g,
    int* __restrict__ sel_idx, float* __restrict__ sel_score)
{
    const int bc = blockIdx.x;
    const int b = bc >> 3, c = bc & 7;
    const int tid = threadIdx.x;
    const float4* bx4 = (const float4*)(boxes + (size_t)b * NN * 4);
    const float* sr = cls + (size_t)b * NN * NC + c;   // fallback only (stride NC)
    int* si = sel_idx + bc * MAX_DET;
    float* ss = sel_score + bc * MAX_DET;

    __shared__ u64 keys[CAP];                  // 8 KB (aliased as fallback bitmask)
    __shared__ unsigned M32[4][CHUNK];
    __shared__ float4 cbox[CHUNK];
    __shared__ float carea[CHUNK];
    __shared__ int   cidx[CHUNK];
    __shared__ float cscore[CHUNK];
    __shared__ unsigned presup[CHUNK];
    __shared__ u64 accmask_s[2];
    __shared__ float4 abox[MAX_DET];
    __shared__ float aarea[MAX_DET];
    __shared__ float rv[NT];
    __shared__ int   ri[NT];
    __shared__ float sboxsh[5];

    const int cnt = cnt_g[bc], total = tot_g[bc];
    const bool full_fb = (cnt > CAP);
    const int inSet = cnt < CAP ? cnt : CAP;

    int n_acc = 0;
    if (!full_fb) {
        for (int i = tid; i < CAP; i += NT)
            keys[i] = (i < inSet) ? cand[(size_t)bc * CAP + i] : 0ull;
        __syncthreads();

        // bitonic sort CAP=1024 desc; 512 thr = 1 CE/thread/pass
        for (int k = 2; k <= CAP; k <<= 1) {
            for (int j = k >> 1; j > 0; j >>= 1) {
                int p = tid;
                int i = 2 * p - (p & (j - 1));
                int ix = i + j;
                bool dir = ((i & k) == 0);
                u64 a = keys[i], bq = keys[ix];
                if ((a < bq) == dir) { keys[i] = bq; keys[ix] = a; }
                __syncthreads();
            }
        }

        // chunked matrix greedy accept
        int base = 0;
        while (n_acc < MAX_DET && base < inSet) {
            int m = inSet - base; if (m > CHUNK) m = CHUNK;

            if (tid < CHUNK) {
                if (tid < m) {
                    u64 key = keys[base + tid];
                    int idx = (int)(~(unsigned)key);
                    unsigned u = (unsigned)(key >> 32);
                    unsigned uo = (u & 0x80000000u) ? (u ^ 0x80000000u) : (~u);
                    float4 bb = bx4[idx];
                    cbox[tid] = bb;
                    carea[tid] = __fmul_rn(__fsub_rn(bb.z, bb.x), __fsub_rn(bb.w, bb.y));
                    cidx[tid] = idx; cscore[tid] = __uint_as_float(uo);
                    presup[tid] = 0u;
                } else presup[tid] = 1u;
            }
            __syncthreads();

            {
                int i = tid & (CHUNK - 1);
                int q = tid >> 7;
                if (i < m) {
                    float4 B = cbox[i];
                    unsigned p = 0;
                    for (int t = q; t < n_acc; t += 4) {
                        float4 A = abox[t];
                        if (iou_ref(A.x, A.y, A.z, A.w, aarea[t],
                                    B.x, B.y, B.z, B.w) > NMS_T) { p = 1; break; }
                    }
                    if (p) atomicOr(&presup[i], 1u);
                    unsigned bits = 0;
                    int j0 = q * 32;
                    for (int jj = 0; jj < 32; ++jj) {
                        int j = j0 + jj;
                        if (j < m && j != i) {
                            float4 A = cbox[j];
                            if (iou_ref(A.x, A.y, A.z, A.w, carea[j],
                                        B.x, B.y, B.z, B.w) > NMS_T)
                                bits |= 1u << jj;
                        }
                    }
                    M32[q][i] = bits;
                }
            }
            __syncthreads();

            if (tid < 64) {
                u64 a0 = 0, a1 = 0;
                int ngroups = (m + 63) >> 6;
                for (int g = 0; g < ngroups; ++g) {
                    int i = g * 64 + tid;
                    unsigned pe = 1; u64 mg = 0;
                    if (i < m) {
                        pe = presup[i];
                        mg = (u64)M32[2 * g][i] | ((u64)M32[2 * g + 1][i] << 32);
                        if (g > 0) {
                            u64 w0 = (u64)M32[0][i] | ((u64)M32[1][i] << 32);
                            if (w0 & a0) pe = 1;
                        }
                    }
                    u64 accw = 0;
                    for (int l = 0; l < 64; ++l) {
                        u64 mgl = __shfl(mg, l, 64);
                        unsigned pel = __shfl(pe, l, 64);
                        if (!pel && (mgl & accw) == 0ull) accw |= 1ull << l;
                    }
                    if (g == 0) a0 = accw; else a1 = accw;
                }
                if (tid == 0) { accmask_s[0] = a0; accmask_s[1] = a1; }
            }
            __syncthreads();

            u64 a0 = accmask_s[0], a1 = accmask_s[1];
            int add = __popcll(a0) + __popcll(a1);
            if (tid < m) {
                int g = tid >> 6, o = tid & 63;
                u64 aw = (g == 0) ? a0 : a1;
                if ((aw >> o) & 1ull) {
                    int rank = (g > 0) ? __popcll(a0) : 0;
                    rank += __popcll(aw & ((1ull << o) - 1ull));
                    int pos = n_acc + rank;
                    if (pos < MAX_DET) {
                        abox[pos] = cbox[tid]; aarea[pos] = carea[tid];
                        si[pos] = cidx[tid]; ss[pos] = cscore[tid];
                    }
                }
            }
            n_acc += add; if (n_acc > MAX_DET) n_acc = MAX_DET;
            base += m;
            __syncthreads();
        }
    }

    const bool part_fb = (!full_fb) && (n_acc < MAX_DET) && (total > inSet);

    if (full_fb || part_fb) {
        // exact fallback; suppression bitmask aliases keys[] (6.25 KB <= 8 KB)
        unsigned* bm = (unsigned*)keys;
        const int BMW = (NN + 31) / 32;
        for (int i = tid; i < BMW; i += NT) bm[i] = 0u;
        __syncthreads();
        if (full_fb) {
            n_acc = 0;
        } else {
            for (int n = tid; n < NN; n += NT) {
                float4 bbn = bx4[n];
                int s = 0;
                for (int t = 0; t < n_acc; ++t) {
                    float4 A = abox[t];
                    if (iou_ref(A.x, A.y, A.z, A.w, aarea[t],
                                bbn.x, bbn.y, bbn.z, bbn.w) > NMS_T) s = 1;
                }
                if (s) atomicOr(&bm[n >> 5], 1u << (n & 31));
            }
        }
        __syncthreads();

        for (int k = n_acc; k < MAX_DET; ++k) {
            float bv = neg_inf(); int bi = 0x7fffffff;
            for (int n = tid; n < NN; n += NT) {
                if (!((bm[n >> 5] >> (n & 31)) & 1u)) {
                    float v = sr[(size_t)n * NC];
                    if (v > SCORE_T && v > bv) { bv = v; bi = n; }
                }
            }
            rv[tid] = bv; ri[tid] = bi;
            __syncthreads();
            for (int s = NT / 2; s > 0; s >>= 1) {
                if (tid < s) {
                    float ov = rv[tid + s]; int oi = ri[tid + s];
                    if (ov > rv[tid] || (ov == rv[tid] && oi < ri[tid])) { rv[tid] = ov; ri[tid] = oi; }
                }
                __syncthreads();
            }
            float mval = rv[0]; int midx = ri[0];
            if (mval == neg_inf()) {
                for (int kk = k + tid; kk < MAX_DET; kk += NT) { si[kk] = 0; ss[kk] = neg_inf(); }
                break;
            }
            if (tid == 0) {
                si[k] = midx; ss[k] = mval;
                float4 sb = bx4[midx];
                sboxsh[0] = sb.x; sboxsh[1] = sb.y; sboxsh[2] = sb.z; sboxsh[3] = sb.w;
                sboxsh[4] = __fmul_rn(__fsub_rn(sb.z, sb.x), __fsub_rn(sb.w, sb.y));
            }
            __syncthreads();
            float ax1 = sboxsh[0], ay1 = sboxsh[1], ax2 = sboxsh[2], ay2 = sboxsh[3];
            float area_a = sboxsh[4];
            for (int n = tid; n < NN; n += NT) {
                float4 bbn = bx4[n];
                if (iou_ref(ax1, ay1, ax2, ay2, area_a,
                            bbn.x, bbn.y, bbn.z, bbn.w) > NMS_T)
                    atomicOr(&bm[n >> 5], 1u << (n & 31));
            }
            __syncthreads();
        }
    } else {
        for (int kk = n_acc + tid; kk < MAX_DET; kk += NT) { si[kk] = 0; ss[kk] = neg_inf(); }
    }
}

// ---------------- T: top-300 via 8-way merge of sorted class lists --------
__global__ __launch_bounds__(1024) void topk_kernel(
    const float* __restrict__ boxes, const float* __restrict__ other,
    const int* __restrict__ sel_idx, const float* __restrict__ sel_score,
    float* __restrict__ out)
{
    const int b = blockIdx.x;
    const int tid = threadIdx.x;
    __shared__ u64 keys[4096];

    // class c at [c*512, c*512+512): slots 0..299 key-descending by construction
    for (int i = tid; i < 4096; i += 1024) {
        int c = i >> 9, o = i & 511;
        u64 key = 0ull;
        if (o < MAX_DET) {
            int m = c * MAX_DET + o;
            float v = sel_score[b * NC * MAX_DET + m];
            unsigned u = __float_as_uint(v);
            u ^= (u & 0x80000000u) ? 0xFFFFFFFFu : 0x80000000u;
            key = ((u64)u << 32) | (unsigned)(~(unsigned)m);
        }
        keys[i] = key;
    }
    __syncthreads();

    // 3 merge rounds: reverse upper half of each segment, then bitonic-merge desc
    for (int seg = 1024; seg <= 4096; seg <<= 1) {
        int half = seg >> 1;
        {   // reversal: total pairs = 4096/4 = 1024 = one iteration
            int p = tid;
            int s = p / (half >> 1), t = p % (half >> 1);
            int i0 = s * seg + half + t;
            int i1 = s * seg + seg - 1 - t;
            u64 a = keys[i0]; keys[i0] = keys[i1]; keys[i1] = a;
        }
        __syncthreads();
        for (int j = half; j > 0; j >>= 1) {
            for (int p = tid; p < 2048; p += 1024) {
                int i = 2 * p - (p & (j - 1));
                int ix = i + j;
                u64 a = keys[i], bq = keys[ix];
                if (a < bq) { keys[i] = bq; keys[ix] = a; }   // desc, uniform dir
            }
            __syncthreads();
        }
    }

    const float4* bx4 = (const float4*)(boxes + (size_t)b * NN * 4);
    const float*  ot  = other + (size_t)b * NN * ND;
    float* ob = out;
    float* os = out + NB * MAX_DET * 4;
    float* ol = os + NB * MAX_DET;
    float* oo = ol + NB * MAX_DET;

    for (int k = tid; k < MAX_DET; k += 1024) {
        u64 key = keys[k];
        unsigned u = (unsigned)(key >> 32);
        unsigned uo = (u & 0x80000000u) ? (u ^ 0x80000000u) : (u ^ 0xFFFFFFFFu);
        float score = __uint_as_float(uo);
        bool valid = isfinite(score);
        float b0=-1.f,b1=-1.f,b2=-1.f,b3=-1.f,scv=-1.f,lab=-1.f,o0=-1.f,o1=-1.f;
        if (valid) {
            int m = (int)(~(unsigned)key);
            int c = m / MAX_DET, slot = m - c * MAX_DET;
            int n = sel_idx[(b * NC + c) * MAX_DET + slot];
            float4 bb = bx4[n];
            b0 = bb.x; b1 = bb.y; b2 = bb.z; b3 = bb.w;
            scv = score; lab = (float)c;
            o0 = ot[n * ND + 0]; o1 = ot[n * ND + 1];
        }
        int base = b * MAX_DET + k;
        ob[base * 4 + 0] = b0; ob[base * 4 + 1] = b1;
        ob[base * 4 + 2] = b2; ob[base * 4 + 3] = b3;
        os[base] = scv; ol[base] = lab;
        oo[base * 2 + 0] = o0; oo[base * 2 + 1] = o1;
    }
}

extern "C" void kernel_launch(void* const* d_in, const int* in_sizes, int n_in,
                              void* d_out, int out_size, void* d_ws, size_t ws_size,
                              hipStream_t stream) {
    const float* boxes = (const float*)d_in[0];
    const float* cls   = (const float*)d_in[1];
    const float* other = (const float*)d_in[2];
    float* out = (float*)d_out;

    // ws: cnt_g[128] | tot_g[128] | cand[128*CAP] u64 | sel_idx | sel_score
    int* cnt_g = (int*)d_ws;
    int* tot_g = cnt_g + NB * NC;
    u64* cand  = (u64*)(tot_g + NB * NC);
    int* sel_idx = (int*)(cand + (size_t)NB * NC * CAP);
    float* sel_score = (float*)(sel_idx + NB * NC * MAX_DET);

    zero_kernel<<<1, 256, 0, stream>>>(cnt_g);
    compact_kernel<<<NB * CBLK, 1024, 0, stream>>>(cls, cnt_g, tot_g, cand);
    nms_kernel<<<NB * NC, NT, 0, stream>>>(boxes, cls, cand, cnt_g, tot_g,
                                           sel_idx, sel_score);
    topk_kernel<<<NB, 1024, 0, stream>>>(boxes, other, sel_idx, sel_score, out);
}

// Round 8
// 87.851 us; speedup vs baseline: 7.7980x; 1.0705x over previous
//
#include <hip/hip_runtime.h>
#include <math.h>
#include <stdint.h>

#define NB 16
#define NN 50000
#define NC 8
#define ND 2
#define MAX_DET 300
#define NMS_T 0.5f
#define SCORE_T 0.05f
#define CAP 1024
#define CUTBIN 252        // s >= 0.984375 ; E[cnt]=781 +- 28, CAP at +8.7 sigma
#define LBUF 128
#define CHUNK 128
#define NT 512
#define NPI (NN * NC)     // 400000 floats per image
#define CBLK 16
#define F4PB (NPI / 4 / CBLK)  // 6250 float4 per compact block

typedef unsigned long long u64;

__device__ __forceinline__ float neg_inf() { return -__builtin_inff(); }

// IoU in the reference's exact op order; _rn forbids FMA contraction.
__device__ __forceinline__ float iou_ref(float ax1, float ay1, float ax2, float ay2,
                                         float area_a,
                                         float bx1, float by1, float bx2, float by2) {
    float x1 = fmaxf(ax1, bx1), y1 = fmaxf(ay1, by1);
    float x2 = fminf(ax2, bx2), y2 = fminf(ay2, by2);
    float inter = __fmul_rn(fmaxf(__fsub_rn(x2, x1), 0.0f),
                            fmaxf(__fsub_rn(y2, y1), 0.0f));
    float area_b = __fmul_rn(__fsub_rn(bx2, bx1), __fsub_rn(by2, by1));
    float uni = __fsub_rn(__fadd_rn(area_a, area_b), inter);
    return __fdiv_rn(inter, fmaxf(uni, 1e-8f));
}

__device__ __forceinline__ u64 score_key(float s, int n) {
    unsigned u = __float_as_uint(s);
    u ^= (u & 0x80000000u) ? 0xFFFFFFFFu : 0x80000000u;
    return ((u64)u << 32) | (unsigned)(~(unsigned)n);
}

// ---------------- C: coalesced fixed-threshold compaction ----------------
__global__ __launch_bounds__(1024) void compact_kernel(
    const float* __restrict__ cls, int* __restrict__ cnt_g,
    int* __restrict__ tot_g, u64* __restrict__ cand)
{
    const int b = blockIdx.x >> 4, t16 = blockIdx.x & 15;
    const int tid = threadIdx.x;
    __shared__ u64 buf[8][LBUF];
    __shared__ int lcnt[8], ltot[8], gbase[8];
    if (tid < 8) { lcnt[tid] = 0; ltot[tid] = 0; }
    __syncthreads();

    const float4* c4 = (const float4*)(cls + (size_t)b * NPI);
    const int f0 = t16 * F4PB, fend = f0 + F4PB;   // f0 even always
    unsigned te[4] = {0,0,0,0}, to[4] = {0,0,0,0};
    const u64 EVEN = 0x5555555555555555ull;

    for (int f = f0 + tid; f < fend; f += 1024) {
        float4 v = c4[f];
        int cb = (f & 1) * 4;
        int n = f >> 1;
        float vv[4] = {v.x, v.y, v.z, v.w};
        #pragma unroll
        for (int k = 0; k < 4; ++k) {
            float s = vv[k];
            if (s > SCORE_T) {
                int bn = (int)(s * 256.0f); if (bn > 255) bn = 255;
                if (bn >= CUTBIN) {
                    int c = cb + k;
                    int pos = atomicAdd(&lcnt[c], 1);
                    u64 key = score_key(s, n);
                    if (pos < LBUF) buf[c][pos] = key;
                    else {
                        int gp = atomicAdd(&cnt_g[b * 8 + c], 1);
                        if (gp < CAP) cand[(size_t)(b * 8 + c) * CAP + gp] = key;
                    }
                }
            }
            u64 bal = __ballot(s > SCORE_T);
            if ((tid & 63) == 0) {
                te[k] += (unsigned)__popcll(bal & EVEN);
                to[k] += (unsigned)__popcll(bal & ~EVEN);
            }
        }
    }
    if ((tid & 63) == 0) {
        #pragma unroll
        for (int k = 0; k < 4; ++k) {
            atomicAdd(&ltot[k], (int)te[k]);
            atomicAdd(&ltot[4 + k], (int)to[k]);
        }
    }
    __syncthreads();
    if (tid < 8) {
        int m = lcnt[tid]; if (m > LBUF) m = LBUF;
        gbase[tid] = atomicAdd(&cnt_g[b * 8 + tid], m);
        atomicAdd(&tot_g[b * 8 + tid], ltot[tid]);
    }
    __syncthreads();
    for (int c = 0; c < 8; ++c) {
        int m = lcnt[c]; if (m > LBUF) m = LBUF;
        int gb = gbase[c];
        for (int i = tid; i < m; i += 1024) {
            int gp = gb + i;
            if (gp < CAP) cand[(size_t)(b * 8 + c) * CAP + gp] = buf[c][i];
        }
    }
}

// ---------------- N: sort + chunked greedy NMS ----------------------------
__global__ __launch_bounds__(NT) void nms_kernel(
    const float* __restrict__ boxes, const float* __restrict__ cls,
    const u64* __restrict__ cand, const int* __restrict__ cnt_g,
    const int* __restrict__ tot_g,
    int* __restrict__ sel_idx, float* __restrict__ sel_score)
{
    const int bc = blockIdx.x;
    const int b = bc >> 3, c = bc & 7;
    const int tid = threadIdx.x;
    const float4* bx4 = (const float4*)(boxes + (size_t)b * NN * 4);
    const float* sr = cls + (size_t)b * NN * NC + c;   // fallback only
    int* si = sel_idx + bc * MAX_DET;
    float* ss = sel_score + bc * MAX_DET;

    __shared__ u64 keys[CAP];
    __shared__ unsigned M32[4][CHUNK];
    __shared__ float4 cbox[CHUNK];
    __shared__ float carea[CHUNK];
    __shared__ int   cidx[CHUNK];
    __shared__ float cscore[CHUNK];
    __shared__ unsigned presup[CHUNK];
    __shared__ u64 accmask_s[2];
    __shared__ float4 abox[MAX_DET];
    __shared__ float aarea[MAX_DET];
    __shared__ float rv[NT];
    __shared__ int   ri[NT];
    __shared__ float sboxsh[5];

    const int cnt = cnt_g[bc], total = tot_g[bc];
    const bool full_fb = (cnt > CAP);
    const int inSet = cnt < CAP ? cnt : CAP;

    int n_acc = 0;
    if (!full_fb) {
        for (int i = tid; i < CAP; i += NT)
            keys[i] = (i < inSet) ? cand[(size_t)bc * CAP + i] : 0ull;
        __syncthreads();

        // bitonic sort desc; j<=64 passes are wave-local (window [2ja,2ja+2j)
        // lies in one wave's 128-elem span) -> lgkmcnt fence instead of barrier
        bool prev_local = false;
        for (int k = 2; k <= CAP; k <<= 1) {
            for (int j = k >> 1; j > 0; j >>= 1) {
                if (j >= 128 && prev_local) __syncthreads();
                int p = tid;
                int i = 2 * p - (p & (j - 1));
                int ix = i + j;
                bool dir = ((i & k) == 0);
                u64 a = keys[i], bq = keys[ix];
                if ((a < bq) == dir) { keys[i] = bq; keys[ix] = a; }
                if (j >= 128) { __syncthreads(); prev_local = false; }
                else { __threadfence_block(); prev_local = true; }
            }
        }
        __syncthreads();

        // chunked matrix greedy accept
        int base = 0;
        while (n_acc < MAX_DET && base < inSet) {
            int m = inSet - base; if (m > CHUNK) m = CHUNK;

            if (tid < CHUNK) {
                if (tid < m) {
                    u64 key = keys[base + tid];
                    int idx = (int)(~(unsigned)key);
                    unsigned u = (unsigned)(key >> 32);
                    unsigned uo = (u & 0x80000000u) ? (u ^ 0x80000000u) : (~u);
                    float4 bb = bx4[idx];
                    cbox[tid] = bb;
                    carea[tid] = __fmul_rn(__fsub_rn(bb.z, bb.x), __fsub_rn(bb.w, bb.y));
                    cidx[tid] = idx; cscore[tid] = __uint_as_float(uo);
                    presup[tid] = 0u;
                } else presup[tid] = 1u;
            }
            __syncthreads();

            {
                int i = tid & (CHUNK - 1);
                int q = tid >> 7;                  // 0..3
                if (i < m) {
                    float4 B = cbox[i];
                    // presup vs accepted list: batched x4 to break LDS latency chain
                    unsigned p = 0;
                    int t = q;
                    for (; t + 12 < n_acc; t += 16) {
                        float4 A0 = abox[t];      float r0 = aarea[t];
                        float4 A1 = abox[t + 4];  float r1 = aarea[t + 4];
                        float4 A2 = abox[t + 8];  float r2 = aarea[t + 8];
                        float4 A3 = abox[t + 12]; float r3 = aarea[t + 12];
                        float i0 = iou_ref(A0.x,A0.y,A0.z,A0.w,r0,B.x,B.y,B.z,B.w);
                        float i1 = iou_ref(A1.x,A1.y,A1.z,A1.w,r1,B.x,B.y,B.z,B.w);
                        float i2 = iou_ref(A2.x,A2.y,A2.z,A2.w,r2,B.x,B.y,B.z,B.w);
                        float i3 = iou_ref(A3.x,A3.y,A3.z,A3.w,r3,B.x,B.y,B.z,B.w);
                        if (i0 > NMS_T || i1 > NMS_T || i2 > NMS_T || i3 > NMS_T) { p = 1; break; }
                    }
                    if (!p) {
                        for (; t < n_acc; t += 4) {
                            float4 A = abox[t];
                            if (iou_ref(A.x,A.y,A.z,A.w,aarea[t],
                                        B.x,B.y,B.z,B.w) > NMS_T) { p = 1; break; }
                        }
                    }
                    if (p) atomicOr(&presup[i], 1u);
                    // intra-chunk matrix: lower triangle only (j < i); greedy
                    // resolve never tests j >= l bits (accw bits are < l).
                    unsigned bits = 0;
                    int j0 = q * 32;
                    int jend = i - j0; if (jend > 32) jend = 32;
                    for (int jj = 0; jj < jend; ++jj) {
                        int j = j0 + jj;
                        float4 A = cbox[j];
                        if (iou_ref(A.x,A.y,A.z,A.w,carea[j],
                                    B.x,B.y,B.z,B.w) > NMS_T)
                            bits |= 1u << jj;
                    }
                    M32[q][i] = bits;
                }
            }
            __syncthreads();

            if (tid < 64) {
                u64 a0 = 0, a1 = 0;
                int ngroups = (m + 63) >> 6;
                for (int g = 0; g < ngroups; ++g) {
                    int i = g * 64 + tid;
                    unsigned pe = 1; u64 mg = 0;
                    if (i < m) {
                        pe = presup[i];
                        mg = (u64)M32[2 * g][i] | ((u64)M32[2 * g + 1][i] << 32);
                        if (g > 0) {
                            u64 w0 = (u64)M32[0][i] | ((u64)M32[1][i] << 32);
                            if (w0 & a0) pe = 1;
                        }
                    }
                    u64 pw = __ballot(pe != 0);
                    u64 accw = 0;
                    for (int l = 0; l < 64; ++l) {
                        u64 mgl = __shfl(mg, l, 64);
                        if (!((pw >> l) & 1ull) && (mgl & accw) == 0ull)
                            accw |= 1ull << l;
                    }
                    if (g == 0) a0 = accw; else a1 = accw;
                }
                if (tid == 0) { accmask_s[0] = a0; accmask_s[1] = a1; }
            }
            __syncthreads();

            u64 a0 = accmask_s[0], a1 = accmask_s[1];
            int add = __popcll(a0) + __popcll(a1);
            if (tid < m) {
                int g = tid >> 6, o = tid & 63;
                u64 aw = (g == 0) ? a0 : a1;
                if ((aw >> o) & 1ull) {
                    int rank = (g > 0) ? __popcll(a0) : 0;
                    rank += __popcll(aw & ((1ull << o) - 1ull));
                    int pos = n_acc + rank;
                    if (pos < MAX_DET) {
                        abox[pos] = cbox[tid]; aarea[pos] = carea[tid];
                        si[pos] = cidx[tid]; ss[pos] = cscore[tid];
                    }
                }
            }
            n_acc += add; if (n_acc > MAX_DET) n_acc = MAX_DET;
            base += m;
            __syncthreads();
        }
    }

    const bool part_fb = (!full_fb) && (n_acc < MAX_DET) && (total > inSet);

    if (full_fb || part_fb) {
        // exact fallback; suppression bitmask aliases keys[]
        unsigned* bm = (unsigned*)keys;
        const int BMW = (NN + 31) / 32;
        for (int i = tid; i < BMW; i += NT) bm[i] = 0u;
        __syncthreads();
        if (full_fb) {
            n_acc = 0;
        } else {
            for (int n = tid; n < NN; n += NT) {
                float4 bbn = bx4[n];
                int s = 0;
                for (int t = 0; t < n_acc; ++t) {
                    float4 A = abox[t];
                    if (iou_ref(A.x, A.y, A.z, A.w, aarea[t],
                                bbn.x, bbn.y, bbn.z, bbn.w) > NMS_T) s = 1;
                }
                if (s) atomicOr(&bm[n >> 5], 1u << (n & 31));
            }
        }
        __syncthreads();

        for (int k = n_acc; k < MAX_DET; ++k) {
            float bv = neg_inf(); int bi = 0x7fffffff;
            for (int n = tid; n < NN; n += NT) {
                if (!((bm[n >> 5] >> (n & 31)) & 1u)) {
                    float v = sr[(size_t)n * NC];
                    if (v > SCORE_T && v > bv) { bv = v; bi = n; }
                }
            }
            rv[tid] = bv; ri[tid] = bi;
            __syncthreads();
            for (int s = NT / 2; s > 0; s >>= 1) {
                if (tid < s) {
                    float ov = rv[tid + s]; int oi = ri[tid + s];
                    if (ov > rv[tid] || (ov == rv[tid] && oi < ri[tid])) { rv[tid] = ov; ri[tid] = oi; }
                }
                __syncthreads();
            }
            float mval = rv[0]; int midx = ri[0];
            if (mval == neg_inf()) {
                for (int kk = k + tid; kk < MAX_DET; kk += NT) { si[kk] = 0; ss[kk] = neg_inf(); }
                break;
            }
            if (tid == 0) {
                si[k] = midx; ss[k] = mval;
                float4 sb = bx4[midx];
                sboxsh[0] = sb.x; sboxsh[1] = sb.y; sboxsh[2] = sb.z; sboxsh[3] = sb.w;
                sboxsh[4] = __fmul_rn(__fsub_rn(sb.z, sb.x), __fsub_rn(sb.w, sb.y));
            }
            __syncthreads();
            float ax1 = sboxsh[0], ay1 = sboxsh[1], ax2 = sboxsh[2], ay2 = sboxsh[3];
            float area_a = sboxsh[4];
            for (int n = tid; n < NN; n += NT) {
                float4 bbn = bx4[n];
                if (iou_ref(ax1, ay1, ax2, ay2, area_a,
                            bbn.x, bbn.y, bbn.z, bbn.w) > NMS_T)
                    atomicOr(&bm[n >> 5], 1u << (n & 31));
            }
            __syncthreads();
        }
    } else {
        for (int kk = n_acc + tid; kk < MAX_DET; kk += NT) { si[kk] = 0; ss[kk] = neg_inf(); }
    }
}

// ---------------- T: top-300 via 8-way merge of sorted class lists --------
__global__ __launch_bounds__(1024) void topk_kernel(
    const float* __restrict__ boxes, const float* __restrict__ other,
    const int* __restrict__ sel_idx, const float* __restrict__ sel_score,
    float* __restrict__ out)
{
    const int b = blockIdx.x;
    const int tid = threadIdx.x;
    __shared__ u64 keys[4096];

    for (int i = tid; i < 4096; i += 1024) {
        int c = i >> 9, o = i & 511;
        u64 key = 0ull;
        if (o < MAX_DET) {
            int m = c * MAX_DET + o;
            float v = sel_score[b * NC * MAX_DET + m];
            unsigned u = __float_as_uint(v);
            u ^= (u & 0x80000000u) ? 0xFFFFFFFFu : 0x80000000u;
            key = ((u64)u << 32) | (unsigned)(~(unsigned)m);
        }
        keys[i] = key;
    }

    for (int seg = 1024; seg <= 4096; seg <<= 1) {
        int half = seg >> 1;
        __syncthreads();
        {   // reverse upper half of each segment (1024 pairs = 1 iter)
            int p = tid;
            int s = p / (half >> 1), t = p % (half >> 1);
            int i0 = s * seg + half + t;
            int i1 = s * seg + seg - 1 - t;
            u64 a = keys[i0]; keys[i0] = keys[i1]; keys[i1] = a;
        }
        __syncthreads();
        for (int j = half; j > 0; j >>= 1) {
            for (int p = tid; p < 2048; p += 1024) {
                int i = 2 * p - (p & (j - 1));
                int ix = i + j;
                u64 a = keys[i], bq = keys[ix];
                if (a < bq) { keys[i] = bq; keys[ix] = a; }
            }
            if (j >= 128) __syncthreads(); else __threadfence_block();
        }
    }
    __syncthreads();

    const float4* bx4 = (const float4*)(boxes + (size_t)b * NN * 4);
    const float*  ot  = other + (size_t)b * NN * ND;
    float* ob = out;
    float* os = out + NB * MAX_DET * 4;
    float* ol = os + NB * MAX_DET;
    float* oo = ol + NB * MAX_DET;

    for (int k = tid; k < MAX_DET; k += 1024) {
        u64 key = keys[k];
        unsigned u = (unsigned)(key >> 32);
        unsigned uo = (u & 0x80000000u) ? (u ^ 0x80000000u) : (u ^ 0xFFFFFFFFu);
        float score = __uint_as_float(uo);
        bool valid = isfinite(score);
        float b0=-1.f,b1=-1.f,b2=-1.f,b3=-1.f,scv=-1.f,lab=-1.f,o0=-1.f,o1=-1.f;
        if (valid) {
            int m = (int)(~(unsigned)key);
            int c = m / MAX_DET, slot = m - c * MAX_DET;
            int n = sel_idx[(b * NC + c) * MAX_DET + slot];
            float4 bb = bx4[n];
            b0 = bb.x; b1 = bb.y; b2 = bb.z; b3 = bb.w;
            scv = score; lab = (float)c;
            o0 = ot[n * ND + 0]; o1 = ot[n * ND + 1];
        }
        int base = b * MAX_DET + k;
        ob[base * 4 + 0] = b0; ob[base * 4 + 1] = b1;
        ob[base * 4 + 2] = b2; ob[base * 4 + 3] = b3;
        os[base] = scv; ol[base] = lab;
        oo[base * 2 + 0] = o0; oo[base * 2 + 1] = o1;
    }
}

extern "C" void kernel_launch(void* const* d_in, const int* in_sizes, int n_in,
                              void* d_out, int out_size, void* d_ws, size_t ws_size,
                              hipStream_t stream) {
    const float* boxes = (const float*)d_in[0];
    const float* cls   = (const float*)d_in[1];
    const float* other = (const float*)d_in[2];
    float* out = (float*)d_out;

    // ws: cnt_g[128] | tot_g[128] | cand[128*CAP] u64 | sel_idx | sel_score
    int* cnt_g = (int*)d_ws;
    int* tot_g = cnt_g + NB * NC;
    u64* cand  = (u64*)(tot_g + NB * NC);
    int* sel_idx = (int*)(cand + (size_t)NB * NC * CAP);
    float* sel_score = (float*)(sel_idx + NB * NC * MAX_DET);

    hipMemsetAsync(cnt_g, 0, 2 * NB * NC * sizeof(int), stream);
    compact_kernel<<<NB * CBLK, 1024, 0, stream>>>(cls, cnt_g, tot_g, cand);
    nms_kernel<<<NB * NC, NT, 0, stream>>>(boxes, cls, cand, cnt_g, tot_g,
                                           sel_idx, sel_score);
    topk_kernel<<<NB, 1024, 0, stream>>>(boxes, other, sel_idx, sel_score, out);
}

// Round 10
// 84.249 us; speedup vs baseline: 8.1314x; 1.0428x over previous
//
#include <hip/hip_runtime.h>
#include <math.h>
#include <stdint.h>

#define NB 16
#define NN 50000
#define NC 8
#define ND 2
#define MAX_DET 300
#define NMS_T 0.5f
#define SCORE_T 0.05f
#define CAP 1024
#define CUTBIN 252        // s >= 0.984375 ; E[cnt]=781 +- 28, CAP at +8.7 sigma
#define LBUF 128
#define CHUNK 128
#define NT 512
#define NPI (NN * NC)
#define CBLK 16
#define F4PB (NPI / 4 / CBLK)  // 6250 float4 per compact block

typedef unsigned long long u64;

__device__ __forceinline__ float neg_inf() { return -__builtin_inff(); }

// IoU in the reference's exact op order; _rn forbids FMA contraction.
__device__ __forceinline__ float iou_ref(float ax1, float ay1, float ax2, float ay2,
                                         float area_a,
                                         float bx1, float by1, float bx2, float by2) {
    float x1 = fmaxf(ax1, bx1), y1 = fmaxf(ay1, by1);
    float x2 = fminf(ax2, bx2), y2 = fminf(ay2, by2);
    float inter = __fmul_rn(fmaxf(__fsub_rn(x2, x1), 0.0f),
                            fmaxf(__fsub_rn(y2, y1), 0.0f));
    float area_b = __fmul_rn(__fsub_rn(bx2, bx1), __fsub_rn(by2, by1));
    float uni = __fsub_rn(__fadd_rn(area_a, area_b), inter);
    return __fdiv_rn(inter, fmaxf(uni, 1e-8f));
}

__device__ __forceinline__ u64 score_key(float s, int n) {
    unsigned u = __float_as_uint(s);
    u ^= (u & 0x80000000u) ? 0xFFFFFFFFu : 0x80000000u;
    return ((u64)u << 32) | (unsigned)(~(unsigned)n);
}

__device__ __forceinline__ u64 shfl_xor_u64(u64 v, int m) {
    unsigned lo = (unsigned)v, hi = (unsigned)(v >> 32);
    lo = __shfl_xor(lo, m, 64);
    hi = __shfl_xor(hi, m, 64);
    return ((u64)hi << 32) | lo;
}

// ---------------- C: coalesced fixed-threshold compaction (filter only) ---
__global__ __launch_bounds__(1024) void compact_kernel(
    const float* __restrict__ cls, int* __restrict__ cnt_g,
    u64* __restrict__ cand)
{
    const int b = blockIdx.x >> 4, t16 = blockIdx.x & 15;
    const int tid = threadIdx.x;
    __shared__ u64 buf[8][LBUF];
    __shared__ int lcnt[8], gbase[8];
    if (tid < 8) lcnt[tid] = 0;
    __syncthreads();

    const float4* c4 = (const float4*)(cls + (size_t)b * NPI);
    const int f0 = t16 * F4PB, fend = f0 + F4PB;

    for (int f = f0 + tid; f < fend; f += 1024) {
        float4 v = c4[f];
        int cb = (f & 1) * 4;
        int n = f >> 1;
        float vv[4] = {v.x, v.y, v.z, v.w};
        #pragma unroll
        for (int k = 0; k < 4; ++k) {
            float s = vv[k];
            if (s > SCORE_T) {
                int bn = (int)(s * 256.0f); if (bn > 255) bn = 255;
                if (bn >= CUTBIN) {
                    int c = cb + k;
                    int pos = atomicAdd(&lcnt[c], 1);
                    u64 key = score_key(s, n);
                    if (pos < LBUF) buf[c][pos] = key;
                    else {
                        int gp = atomicAdd(&cnt_g[b * 8 + c], 1);
                        if (gp < CAP) cand[(size_t)(b * 8 + c) * CAP + gp] = key;
                    }
                }
            }
        }
    }
    __syncthreads();
    if (tid < 8) {
        int m = lcnt[tid]; if (m > LBUF) m = LBUF;
        gbase[tid] = atomicAdd(&cnt_g[b * 8 + tid], m);
    }
    __syncthreads();
    for (int c = 0; c < 8; ++c) {
        int m = lcnt[c]; if (m > LBUF) m = LBUF;
        int gb = gbase[c];
        for (int i = tid; i < m; i += 1024) {
            int gp = gb + i;
            if (gp < CAP) cand[(size_t)(b * 8 + c) * CAP + gp] = buf[c][i];
        }
    }
}

// ---------------- S: hybrid register/LDS bitonic sort (desc) --------------
__global__ __launch_bounds__(512) void sort_kernel(
    u64* __restrict__ cand, const int* __restrict__ cnt_g)
{
    const int bc = blockIdx.x;
    const int tid = threadIdx.x;
    const int lane = tid & 63, widx = tid >> 6;
    const int cnt = cnt_g[bc];
    if (cnt > CAP) return;                 // full-fallback path owns this bc
    u64* g = cand + (size_t)bc * CAP;
    __shared__ u64 lds[CAP];

    const int p0 = widx * 128 + lane, p1 = p0 + 64;
    u64 v0 = (p0 < cnt) ? g[p0] : 0ull;
    u64 v1 = (p1 < cnt) ? g[p1] : 0ull;

    // wave-local stages k=2..128 (registers). NOTE: dir must be computed
    // per-element: at k=64, (p1&k) != (p0&k) (R9 bug).
    #pragma unroll
    for (int k = 2; k <= 128; k <<= 1) {
        #pragma unroll
        for (int j = k >> 1; j > 0; j >>= 1) {
            if (j == 64) {                 // pair (p0,p1) within lane
                bool dir = ((p0 & k) == 0);
                if ((v0 < v1) == dir) { u64 t = v0; v0 = v1; v1 = t; }
            } else {
                bool lower = ((lane & j) == 0);
                bool dir0 = ((p0 & k) == 0);
                bool dir1 = ((p1 & k) == 0);
                u64 o0 = shfl_xor_u64(v0, j);
                u64 mx0 = v0 > o0 ? v0 : o0, mn0 = v0 > o0 ? o0 : v0;
                v0 = (lower == dir0) ? mx0 : mn0;
                u64 o1 = shfl_xor_u64(v1, j);
                u64 mx1 = v1 > o1 ? v1 : o1, mn1 = v1 > o1 ? o1 : v1;
                v1 = (lower == dir1) ? mx1 : mn1;
            }
        }
    }
    // cross-wave stages k=256,512,1024
    for (int k = 256; k <= CAP; k <<= 1) {
        lds[p0] = v0; lds[p1] = v1;
        __syncthreads();
        for (int j = k >> 1; j >= 128; j >>= 1) {
            int p = tid;
            int i = 2 * p - (p & (j - 1));
            int ix = i + j;
            bool dir = ((i & k) == 0);
            u64 a = lds[i], b2 = lds[ix];
            if ((a < b2) == dir) { lds[i] = b2; lds[ix] = a; }
            __syncthreads();
        }
        v0 = lds[p0]; v1 = lds[p1];
        {   // j = 64: pair (p0,p1), dir from lower index p0
            bool dir = ((p0 & k) == 0);
            if ((v0 < v1) == dir) { u64 t = v0; v0 = v1; v1 = t; }
        }
        #pragma unroll
        for (int j = 32; j > 0; j >>= 1) {   // k>=256: (p1&k)==(p0&k)
            bool lower = ((lane & j) == 0);
            bool dir = ((p0 & k) == 0);
            u64 o0 = shfl_xor_u64(v0, j);
            u64 mx0 = v0 > o0 ? v0 : o0, mn0 = v0 > o0 ? o0 : v0;
            v0 = (lower == dir) ? mx0 : mn0;
            u64 o1 = shfl_xor_u64(v1, j);
            u64 mx1 = v1 > o1 ? v1 : o1, mn1 = v1 > o1 ? o1 : v1;
            v1 = (lower == dir) ? mx1 : mn1;
        }
        if (k < CAP) __syncthreads();
    }
    g[p0] = v0; g[p1] = v1;
}

// ---------------- G: pipelined chunked greedy NMS --------------------------
__global__ __launch_bounds__(NT) void greedy_kernel(
    const float* __restrict__ boxes, const float* __restrict__ cls,
    const u64* __restrict__ cand, const int* __restrict__ cnt_g,
    int* __restrict__ sel_idx, float* __restrict__ sel_score)
{
    const int bc = blockIdx.x;
    const int b = bc >> 3, c = bc & 7;
    const int tid = threadIdx.x;
    const float4* bx4 = (const float4*)(boxes + (size_t)b * NN * 4);
    const float* sr = cls + (size_t)b * NN * NC + c;   // fallback only
    const u64* g = cand + (size_t)bc * CAP;
    int* si = sel_idx + bc * MAX_DET;
    float* ss = sel_score + bc * MAX_DET;

    __shared__ float4 cbox2[2][CHUNK];
    __shared__ float  carea2[2][CHUNK];
    __shared__ int    cidx2[2][CHUNK];
    __shared__ float  cscore2[2][CHUNK];
    __shared__ unsigned M32[4][CHUNK];
    __shared__ unsigned presup4[4][CHUNK];    // race-free: one slot per q
    __shared__ u64 accmask_s[2];
    __shared__ float4 abox[MAX_DET];
    __shared__ float aarea[MAX_DET];
    __shared__ unsigned bm[(NN + 31) / 32];   // fallback bitmask
    __shared__ float rv[NT];
    __shared__ int   ri[NT];
    __shared__ float sboxsh[5];

    const int cnt = cnt_g[bc];
    const bool full_fb = (cnt > CAP);
    const int inSet = cnt < CAP ? cnt : CAP;

    int n_acc = 0;
    if (!full_fb) {
        // gather chunk 0
        if (tid < CHUNK && tid < inSet) {
            u64 key = g[tid];
            int idx = (int)(~(unsigned)key);
            unsigned u = (unsigned)(key >> 32);
            unsigned uo = (u & 0x80000000u) ? (u ^ 0x80000000u) : (~u);
            float4 bb = bx4[idx];
            cbox2[0][tid] = bb;
            carea2[0][tid] = __fmul_rn(__fsub_rn(bb.z, bb.x), __fsub_rn(bb.w, bb.y));
            cidx2[0][tid] = idx; cscore2[0][tid] = __uint_as_float(uo);
        }
        __syncthreads();

        int base = 0, cur = 0;
        while (n_acc < MAX_DET && base < inSet) {
            int m = inSet - base; if (m > CHUNK) m = CHUNK;

            // presup (vs accepted) + lower-triangle matrix, all 512 threads
            {
                int i = tid & (CHUNK - 1);
                int q = tid >> 7;
                if (i < m) {
                    float4 B = cbox2[cur][i];
                    unsigned p = 0;
                    int t = q;
                    for (; t + 12 < n_acc; t += 16) {
                        float4 A0 = abox[t];      float r0 = aarea[t];
                        float4 A1 = abox[t + 4];  float r1 = aarea[t + 4];
                        float4 A2 = abox[t + 8];  float r2 = aarea[t + 8];
                        float4 A3 = abox[t + 12]; float r3 = aarea[t + 12];
                        float i0 = iou_ref(A0.x,A0.y,A0.z,A0.w,r0,B.x,B.y,B.z,B.w);
                        float i1 = iou_ref(A1.x,A1.y,A1.z,A1.w,r1,B.x,B.y,B.z,B.w);
                        float i2 = iou_ref(A2.x,A2.y,A2.z,A2.w,r2,B.x,B.y,B.z,B.w);
                        float i3 = iou_ref(A3.x,A3.y,A3.z,A3.w,r3,B.x,B.y,B.z,B.w);
                        if (i0 > NMS_T || i1 > NMS_T || i2 > NMS_T || i3 > NMS_T) { p = 1; break; }
                    }
                    if (!p) {
                        for (; t < n_acc; t += 4) {
                            float4 A = abox[t];
                            if (iou_ref(A.x,A.y,A.z,A.w,aarea[t],
                                        B.x,B.y,B.z,B.w) > NMS_T) { p = 1; break; }
                        }
                    }
                    presup4[q][i] = p;            // unconditional store, no race
                    unsigned bits = 0;
                    int j0 = q * 32;
                    int jend = i - j0; if (jend > 32) jend = 32;
                    for (int jj = 0; jj < jend; ++jj) {
                        int j = j0 + jj;
                        float4 A = cbox2[cur][j];
                        if (iou_ref(A.x,A.y,A.z,A.w,carea2[cur][j],
                                    B.x,B.y,B.z,B.w) > NMS_T)
                            bits |= 1u << jj;
                    }
                    M32[q][i] = bits;
                }
            }
            __syncthreads();

            int nbase = base + m;
            if (tid < 64) {
                // wave 0: serial greedy resolve
                u64 a0 = 0, a1 = 0;
                int ngroups = (m + 63) >> 6;
                for (int gg = 0; gg < ngroups; ++gg) {
                    int i = gg * 64 + tid;
                    unsigned pe = 1; u64 mg = 0;
                    if (i < m) {
                        pe = presup4[0][i] | presup4[1][i] | presup4[2][i] | presup4[3][i];
                        mg = (u64)M32[2 * gg][i] | ((u64)M32[2 * gg + 1][i] << 32);
                        if (gg > 0) {
                            u64 w0 = (u64)M32[0][i] | ((u64)M32[1][i] << 32);
                            if (w0 & a0) pe = 1;
                        }
                    }
                    u64 pw = __ballot(pe != 0);
                    u64 accw = 0;
                    for (int l = 0; l < 64; ++l) {
                        u64 row = __shfl(mg, l, 64);
                        if (!((pw >> l) & 1ull) && (row & accw) == 0ull)
                            accw |= 1ull << l;
                    }
                    if (gg == 0) a0 = accw; else a1 = accw;
                }
                if (tid == 0) { accmask_s[0] = a0; accmask_s[1] = a1; }
            } else if (nbase < inSet) {
                // waves 1-7: gather next chunk (hidden under resolve)
                int w = tid - 64;
                if (w < CHUNK && nbase + w < inSet) {
                    u64 key = g[nbase + w];
                    int idx = (int)(~(unsigned)key);
                    unsigned u = (unsigned)(key >> 32);
                    unsigned uo = (u & 0x80000000u) ? (u ^ 0x80000000u) : (~u);
                    float4 bb = bx4[idx];
                    cbox2[cur ^ 1][w] = bb;
                    carea2[cur ^ 1][w] = __fmul_rn(__fsub_rn(bb.z, bb.x), __fsub_rn(bb.w, bb.y));
                    cidx2[cur ^ 1][w] = idx; cscore2[cur ^ 1][w] = __uint_as_float(uo);
                }
            }
            __syncthreads();

            u64 a0 = accmask_s[0], a1 = accmask_s[1];
            int add = __popcll(a0) + __popcll(a1);
            if (tid < m) {
                int gg = tid >> 6, o = tid & 63;
                u64 aw = (gg == 0) ? a0 : a1;
                if ((aw >> o) & 1ull) {
                    int rank = (gg > 0) ? __popcll(a0) : 0;
                    rank += __popcll(aw & ((1ull << o) - 1ull));
                    int pos = n_acc + rank;
                    if (pos < MAX_DET) {
                        abox[pos] = cbox2[cur][tid]; aarea[pos] = carea2[cur][tid];
                        si[pos] = cidx2[cur][tid]; ss[pos] = cscore2[cur][tid];
                    }
                }
            }
            n_acc += add; if (n_acc > MAX_DET) n_acc = MAX_DET;
            base = nbase; cur ^= 1;
            __syncthreads();
        }
    }

    const bool part_fb = (!full_fb) && (n_acc < MAX_DET);

    if (full_fb || part_fb) {
        // ======== exact fallback: bitmask argmax loop ========
        const int BMW = (NN + 31) / 32;
        for (int i = tid; i < BMW; i += NT) bm[i] = 0u;
        __syncthreads();
        if (full_fb) {
            n_acc = 0;
        } else {
            for (int n = tid; n < NN; n += NT) {
                float4 bbn = bx4[n];
                int s = 0;
                for (int t = 0; t < n_acc; ++t) {
                    float4 A = abox[t];
                    if (iou_ref(A.x, A.y, A.z, A.w, aarea[t],
                                bbn.x, bbn.y, bbn.z, bbn.w) > NMS_T) s = 1;
                }
                if (s) atomicOr(&bm[n >> 5], 1u << (n & 31));
            }
        }
        __syncthreads();

        for (int k = n_acc; k < MAX_DET; ++k) {
            float bv = neg_inf(); int bi = 0x7fffffff;
            for (int n = tid; n < NN; n += NT) {
                if (!((bm[n >> 5] >> (n & 31)) & 1u)) {
                    float v = sr[(size_t)n * NC];
                    if (v > SCORE_T && v > bv) { bv = v; bi = n; }
                }
            }
            rv[tid] = bv; ri[tid] = bi;
            __syncthreads();
            for (int s = NT / 2; s > 0; s >>= 1) {
                if (tid < s) {
                    float ov = rv[tid + s]; int oi = ri[tid + s];
                    if (ov > rv[tid] || (ov == rv[tid] && oi < ri[tid])) { rv[tid] = ov; ri[tid] = oi; }
                }
                __syncthreads();
            }
            float mval = rv[0]; int midx = ri[0];
            if (mval == neg_inf()) {
                for (int kk = k + tid; kk < MAX_DET; kk += NT) { si[kk] = 0; ss[kk] = neg_inf(); }
                break;
            }
            if (tid == 0) {
                si[k] = midx; ss[k] = mval;
                float4 sb = bx4[midx];
                sboxsh[0] = sb.x; sboxsh[1] = sb.y; sboxsh[2] = sb.z; sboxsh[3] = sb.w;
                sboxsh[4] = __fmul_rn(__fsub_rn(sb.z, sb.x), __fsub_rn(sb.w, sb.y));
            }
            __syncthreads();
            float ax1 = sboxsh[0], ay1 = sboxsh[1], ax2 = sboxsh[2], ay2 = sboxsh[3];
            float area_a = sboxsh[4];
            for (int n = tid; n < NN; n += NT) {
                float4 bbn = bx4[n];
                if (iou_ref(ax1, ay1, ax2, ay2, area_a,
                            bbn.x, bbn.y, bbn.z, bbn.w) > NMS_T)
                    atomicOr(&bm[n >> 5], 1u << (n & 31));
            }
            __syncthreads();
        }
    } else {
        for (int kk = n_acc + tid; kk < MAX_DET; kk += NT) { si[kk] = 0; ss[kk] = neg_inf(); }
    }
}

// ---------------- T: top-300 via 8-way merge of sorted class lists --------
__global__ __launch_bounds__(1024) void topk_kernel(
    const float* __restrict__ boxes, const float* __restrict__ other,
    const int* __restrict__ sel_idx, const float* __restrict__ sel_score,
    float* __restrict__ out)
{
    const int b = blockIdx.x;
    const int tid = threadIdx.x;
    __shared__ u64 keys[4096];

    for (int i = tid; i < 4096; i += 1024) {
        int c = i >> 9, o = i & 511;
        u64 key = 0ull;
        if (o < MAX_DET) {
            int m = c * MAX_DET + o;
            float v = sel_score[b * NC * MAX_DET + m];
            unsigned u = __float_as_uint(v);
            u ^= (u & 0x80000000u) ? 0xFFFFFFFFu : 0x80000000u;
            key = ((u64)u << 32) | (unsigned)(~(unsigned)m);
        }
        keys[i] = key;
    }

    for (int seg = 1024; seg <= 4096; seg <<= 1) {
        int half = seg >> 1;
        __syncthreads();
        {
            int p = tid;
            int s = p / (half >> 1), t = p % (half >> 1);
            int i0 = s * seg + half + t;
            int i1 = s * seg + seg - 1 - t;
            u64 a = keys[i0]; keys[i0] = keys[i1]; keys[i1] = a;
        }
        __syncthreads();
        for (int j = half; j > 0; j >>= 1) {
            for (int p = tid; p < 2048; p += 1024) {
                int i = 2 * p - (p & (j - 1));
                int ix = i + j;
                u64 a = keys[i], bq = keys[ix];
                if (a < bq) { keys[i] = bq; keys[ix] = a; }
            }
            if (j >= 128) __syncthreads(); else __threadfence_block();
        }
    }
    __syncthreads();

    const float4* bx4 = (const float4*)(boxes + (size_t)b * NN * 4);
    const float*  ot  = other + (size_t)b * NN * ND;
    float* ob = out;
    float* os = out + NB * MAX_DET * 4;
    float* ol = os + NB * MAX_DET;
    float* oo = ol + NB * MAX_DET;

    for (int k = tid; k < MAX_DET; k += 1024) {
        u64 key = keys[k];
        unsigned u = (unsigned)(key >> 32);
        unsigned uo = (u & 0x80000000u) ? (u ^ 0x80000000u) : (u ^ 0xFFFFFFFFu);
        float score = __uint_as_float(uo);
        bool valid = isfinite(score);
        float b0=-1.f,b1=-1.f,b2=-1.f,b3=-1.f,scv=-1.f,lab=-1.f,o0=-1.f,o1=-1.f;
        if (valid) {
            int m = (int)(~(unsigned)key);
            int c = m / MAX_DET, slot = m - c * MAX_DET;
            int n = sel_idx[(b * NC + c) * MAX_DET + slot];
            float4 bb = bx4[n];
            b0 = bb.x; b1 = bb.y; b2 = bb.z; b3 = bb.w;
            scv = score; lab = (float)c;
            o0 = ot[n * ND + 0]; o1 = ot[n * ND + 1];
        }
        int base = b * MAX_DET + k;
        ob[base * 4 + 0] = b0; ob[base * 4 + 1] = b1;
        ob[base * 4 + 2] = b2; ob[base * 4 + 3] = b3;
        os[base] = scv; ol[base] = lab;
        oo[base * 2 + 0] = o0; oo[base * 2 + 1] = o1;
    }
}

extern "C" void kernel_launch(void* const* d_in, const int* in_sizes, int n_in,
                              void* d_out, int out_size, void* d_ws, size_t ws_size,
                              hipStream_t stream) {
    const float* boxes = (const float*)d_in[0];
    const float* cls   = (const float*)d_in[1];
    const float* other = (const float*)d_in[2];
    float* out = (float*)d_out;

    // ws: cnt_g[256 slack] | cand[128*CAP] u64 | sel_idx | sel_score
    int* cnt_g = (int*)d_ws;
    u64* cand  = (u64*)(cnt_g + NB * NC * 2);
    int* sel_idx = (int*)(cand + (size_t)NB * NC * CAP);
    float* sel_score = (float*)(sel_idx + NB * NC * MAX_DET);

    hipMemsetAsync(cnt_g, 0, NB * NC * sizeof(int), stream);
    compact_kernel<<<NB * CBLK, 1024, 0, stream>>>(cls, cnt_g, cand);
    sort_kernel<<<NB * NC, 512, 0, stream>>>(cand, cnt_g);
    greedy_kernel<<<NB * NC, NT, 0, stream>>>(boxes, cls, cand, cnt_g,
                                              sel_idx, sel_score);
    topk_kernel<<<NB, 1024, 0, stream>>>(boxes, other, sel_idx, sel_score, out);
}

// Round 11
// 72.737 us; speedup vs baseline: 9.4184x; 1.1583x over previous
//
#include <hip/hip_runtime.h>
#include <math.h>
#include <stdint.h>

#define NB 16
#define NN 50000
#define NC 8
#define ND 2
#define MAX_DET 300
#define NMS_T 0.5f
#define SCORE_T 0.05f
#define CAP 1024
#define CUTBIN 252        // s >= 0.984375 ; E[cnt]=781 +- 28, CAP at +8.7 sigma
#define LBUF 128
#define CHUNK 128
#define NT 512
#define NPI (NN * NC)
#define CBLK 32
#define F4PB (NPI / 4 / CBLK)  // 3125 float4 per compact block

typedef unsigned long long u64;

__device__ __forceinline__ float neg_inf() { return -__builtin_inff(); }

// Bit-exact IoU > 0.5 test, division-free:
// RN(inter/umax) > 0.5  <=>  inter > 0.5*umax   (0.5*umax exact: pow2 scale;
// no float quotient falls in the RN-ambiguous window around 0.5 — the tie
// midpoint requires a 25-bit mantissa operand, unrepresentable).
__device__ __forceinline__ bool iou_gt(float ax1, float ay1, float ax2, float ay2,
                                       float area_a,
                                       float bx1, float by1, float bx2, float by2) {
    float x1 = fmaxf(ax1, bx1), y1 = fmaxf(ay1, by1);
    float x2 = fminf(ax2, bx2), y2 = fminf(ay2, by2);
    float inter = __fmul_rn(fmaxf(__fsub_rn(x2, x1), 0.0f),
                            fmaxf(__fsub_rn(y2, y1), 0.0f));
    float area_b = __fmul_rn(__fsub_rn(bx2, bx1), __fsub_rn(by2, by1));
    float uni = __fsub_rn(__fadd_rn(area_a, area_b), inter);
    return inter > __fmul_rn(0.5f, fmaxf(uni, 1e-8f));
}

__device__ __forceinline__ u64 score_key(float s, int n) {
    unsigned u = __float_as_uint(s);
    u ^= (u & 0x80000000u) ? 0xFFFFFFFFu : 0x80000000u;
    return ((u64)u << 32) | (unsigned)(~(unsigned)n);
}

__device__ __forceinline__ u64 shfl_xor_u64(u64 v, int m) {
    unsigned lo = (unsigned)v, hi = (unsigned)(v >> 32);
    lo = __shfl_xor(lo, m, 64);
    hi = __shfl_xor(hi, m, 64);
    return ((u64)hi << 32) | lo;
}

// ---------------- C: coalesced fixed-threshold compaction -----------------
__global__ __launch_bounds__(1024) void compact_kernel(
    const float* __restrict__ cls, int* __restrict__ cnt_g,
    u64* __restrict__ cand)
{
    const int b = blockIdx.x >> 5, t32 = blockIdx.x & 31;
    const int tid = threadIdx.x;
    __shared__ u64 buf[8][LBUF];
    __shared__ int lcnt[8], gbase[8];
    if (tid < 8) lcnt[tid] = 0;
    __syncthreads();

    const float4* c4 = (const float4*)(cls + (size_t)b * NPI);
    const int f0 = t32 * F4PB, fend = f0 + F4PB;

    for (int f = f0 + tid; f < fend; f += 1024) {
        float4 v = c4[f];
        int cb = (f & 1) * 4;      // class from element parity; alignment-free
        int n = f >> 1;
        float vv[4] = {v.x, v.y, v.z, v.w};
        #pragma unroll
        for (int k = 0; k < 4; ++k) {
            float s = vv[k];
            if (s > SCORE_T) {
                int bn = (int)(s * 256.0f); if (bn > 255) bn = 255;
                if (bn >= CUTBIN) {
                    int c = cb + k;
                    int pos = atomicAdd(&lcnt[c], 1);
                    u64 key = score_key(s, n);
                    if (pos < LBUF) buf[c][pos] = key;
                    else {   // rare overflow: exact via direct global append
                        int gp = atomicAdd(&cnt_g[b * 8 + c], 1);
                        if (gp < CAP) cand[(size_t)(b * 8 + c) * CAP + gp] = key;
                    }
                }
            }
        }
    }
    __syncthreads();
    if (tid < 8) {
        int m = lcnt[tid]; if (m > LBUF) m = LBUF;
        gbase[tid] = atomicAdd(&cnt_g[b * 8 + tid], m);
    }
    __syncthreads();
    for (int c = 0; c < 8; ++c) {
        int m = lcnt[c]; if (m > LBUF) m = LBUF;
        int gb = gbase[c];
        for (int i = tid; i < m; i += 1024) {
            int gp = gb + i;
            if (gp < CAP) cand[(size_t)(b * 8 + c) * CAP + gp] = buf[c][i];
        }
    }
}

// ---------------- N: fused sort (reg/LDS bitonic) + chunked greedy ---------
__global__ __launch_bounds__(NT) void nms_fused(
    const float* __restrict__ boxes, const float* __restrict__ cls,
    const u64* __restrict__ cand, const int* __restrict__ cnt_g,
    int* __restrict__ sel_idx, float* __restrict__ sel_score)
{
    const int bc = blockIdx.x;
    const int b = bc >> 3, c = bc & 7;
    const int tid = threadIdx.x;
    const int lane = tid & 63, widx = tid >> 6;
    const float4* bx4 = (const float4*)(boxes + (size_t)b * NN * 4);
    const float* sr = cls + (size_t)b * NN * NC + c;   // fallback only
    const u64* g = cand + (size_t)bc * CAP;
    int* si = sel_idx + bc * MAX_DET;
    float* ss = sel_score + bc * MAX_DET;

    __shared__ u64 keys[CAP];                  // sort scratch + sorted keys
    __shared__ float4 cbox2[2][CHUNK];
    __shared__ float  carea2[2][CHUNK];
    __shared__ int    cidx2[2][CHUNK];
    __shared__ float  cscore2[2][CHUNK];
    __shared__ unsigned M32[4][CHUNK];
    __shared__ unsigned presup4[4][CHUNK];     // race-free: one slot per q
    __shared__ u64 accmask_s[2];
    __shared__ float4 abox[MAX_DET];
    __shared__ float aarea[MAX_DET];
    __shared__ unsigned bm[(NN + 31) / 32];    // fallback bitmask
    __shared__ float rv[NT];
    __shared__ int   ri[NT];
    __shared__ float sboxsh[5];

    const int cnt = cnt_g[bc];
    const bool full_fb = (cnt > CAP);
    const int inSet = cnt < CAP ? cnt : CAP;

    int n_acc = 0;
    if (!full_fb) {
        // ===== hybrid register/LDS bitonic sort, descending =====
        const int p0 = widx * 128 + lane, p1 = p0 + 64;
        u64 v0 = (p0 < cnt) ? g[p0] : 0ull;
        u64 v1 = (p1 < cnt) ? g[p1] : 0ull;

        #pragma unroll
        for (int k = 2; k <= 128; k <<= 1) {
            #pragma unroll
            for (int j = k >> 1; j > 0; j >>= 1) {
                if (j == 64) {                 // pair (p0,p1) within lane
                    bool dir = ((p0 & k) == 0);
                    if ((v0 < v1) == dir) { u64 t = v0; v0 = v1; v1 = t; }
                } else {
                    bool lower = ((lane & j) == 0);
                    bool dir0 = ((p0 & k) == 0);
                    bool dir1 = ((p1 & k) == 0);  // differs from dir0 at k=64
                    u64 o0 = shfl_xor_u64(v0, j);
                    u64 mx0 = v0 > o0 ? v0 : o0, mn0 = v0 > o0 ? o0 : v0;
                    v0 = (lower == dir0) ? mx0 : mn0;
                    u64 o1 = shfl_xor_u64(v1, j);
                    u64 mx1 = v1 > o1 ? v1 : o1, mn1 = v1 > o1 ? o1 : v1;
                    v1 = (lower == dir1) ? mx1 : mn1;
                }
            }
        }
        for (int k = 256; k <= CAP; k <<= 1) {
            keys[p0] = v0; keys[p1] = v1;
            __syncthreads();
            for (int j = k >> 1; j >= 128; j >>= 1) {
                int p = tid;
                int i = 2 * p - (p & (j - 1));
                int ix = i + j;
                bool dir = ((i & k) == 0);
                u64 a = keys[i], b2 = keys[ix];
                if ((a < b2) == dir) { keys[i] = b2; keys[ix] = a; }
                __syncthreads();
            }
            v0 = keys[p0]; v1 = keys[p1];
            {
                bool dir = ((p0 & k) == 0);
                if ((v0 < v1) == dir) { u64 t = v0; v0 = v1; v1 = t; }
            }
            #pragma unroll
            for (int j = 32; j > 0; j >>= 1) {   // k>=256: (p1&k)==(p0&k)
                bool lower = ((lane & j) == 0);
                bool dir = ((p0 & k) == 0);
                u64 o0 = shfl_xor_u64(v0, j);
                u64 mx0 = v0 > o0 ? v0 : o0, mn0 = v0 > o0 ? o0 : v0;
                v0 = (lower == dir) ? mx0 : mn0;
                u64 o1 = shfl_xor_u64(v1, j);
                u64 mx1 = v1 > o1 ? v1 : o1, mn1 = v1 > o1 ? o1 : v1;
                v1 = (lower == dir) ? mx1 : mn1;
            }
            __syncthreads();                   // before rewriting keys
        }
        keys[p0] = v0; keys[p1] = v1;
        __syncthreads();

        // ===== chunked greedy accept (pipelined gather) =====
        if (tid < CHUNK && tid < inSet) {
            u64 key = keys[tid];
            int idx = (int)(~(unsigned)key);
            unsigned u = (unsigned)(key >> 32);
            unsigned uo = (u & 0x80000000u) ? (u ^ 0x80000000u) : (~u);
            float4 bb = bx4[idx];
            cbox2[0][tid] = bb;
            carea2[0][tid] = __fmul_rn(__fsub_rn(bb.z, bb.x), __fsub_rn(bb.w, bb.y));
            cidx2[0][tid] = idx; cscore2[0][tid] = __uint_as_float(uo);
        }
        __syncthreads();

        int base = 0, cur = 0;
        while (n_acc < MAX_DET && base < inSet) {
            int m = inSet - base; if (m > CHUNK) m = CHUNK;

            // presup (vs accepted) + lower-triangle matrix, all 512 threads
            {
                int i = tid & (CHUNK - 1);
                int q = tid >> 7;
                if (i < m) {
                    float4 B = cbox2[cur][i];
                    unsigned p = 0;
                    int t = q;
                    for (; t + 12 < n_acc; t += 16) {
                        float4 A0 = abox[t];      float r0 = aarea[t];
                        float4 A1 = abox[t + 4];  float r1 = aarea[t + 4];
                        float4 A2 = abox[t + 8];  float r2 = aarea[t + 8];
                        float4 A3 = abox[t + 12]; float r3 = aarea[t + 12];
                        bool s0 = iou_gt(A0.x,A0.y,A0.z,A0.w,r0,B.x,B.y,B.z,B.w);
                        bool s1 = iou_gt(A1.x,A1.y,A1.z,A1.w,r1,B.x,B.y,B.z,B.w);
                        bool s2 = iou_gt(A2.x,A2.y,A2.z,A2.w,r2,B.x,B.y,B.z,B.w);
                        bool s3 = iou_gt(A3.x,A3.y,A3.z,A3.w,r3,B.x,B.y,B.z,B.w);
                        if (s0 || s1 || s2 || s3) { p = 1; break; }
                    }
                    if (!p) {
                        for (; t < n_acc; t += 4) {
                            float4 A = abox[t];
                            if (iou_gt(A.x,A.y,A.z,A.w,aarea[t],
                                       B.x,B.y,B.z,B.w)) { p = 1; break; }
                        }
                    }
                    presup4[q][i] = p;
                    unsigned bits = 0;
                    int j0 = q * 32;
                    int jend = i - j0; if (jend > 32) jend = 32;
                    for (int jj = 0; jj < jend; ++jj) {
                        int j = j0 + jj;
                        float4 A = cbox2[cur][j];
                        if (iou_gt(A.x,A.y,A.z,A.w,carea2[cur][j],
                                   B.x,B.y,B.z,B.w))
                            bits |= 1u << jj;
                    }
                    M32[q][i] = bits;
                }
            }
            __syncthreads();

            int nbase = base + m;
            if (tid < 64) {
                // wave 0: ballot-driven greedy resolve (accepted-only iters)
                u64 a0 = 0, a1 = 0;
                int ngroups = (m + 63) >> 6;
                for (int gg = 0; gg < ngroups; ++gg) {
                    int i = gg * 64 + tid;
                    unsigned pe = 1; u64 mg = 0;
                    if (i < m) {
                        pe = presup4[0][i] | presup4[1][i] | presup4[2][i] | presup4[3][i];
                        mg = (u64)M32[2 * gg][i] | ((u64)M32[2 * gg + 1][i] << 32);
                        if (gg > 0) {
                            u64 w0 = (u64)M32[0][i] | ((u64)M32[1][i] << 32);
                            if (w0 & a0) pe = 1;
                        }
                    }
                    u64 rem = ~__ballot(pe != 0);    // candidates still eligible
                    u64 accw = 0;
                    while (rem) {
                        int l = __builtin_ctzll(rem);
                        accw |= 1ull << l;
                        rem &= ~(1ull << l);
                        u64 supm = __ballot(((mg >> l) & 1ull) != 0);
                        rem &= ~supm;
                    }
                    if (gg == 0) a0 = accw; else a1 = accw;
                }
                if (tid == 0) { accmask_s[0] = a0; accmask_s[1] = a1; }
            } else if (nbase < inSet) {
                // waves 1-7: gather next chunk (hidden under resolve)
                int w = tid - 64;
                if (w < CHUNK && nbase + w < inSet) {
                    u64 key = keys[nbase + w];
                    int idx = (int)(~(unsigned)key);
                    unsigned u = (unsigned)(key >> 32);
                    unsigned uo = (u & 0x80000000u) ? (u ^ 0x80000000u) : (~u);
                    float4 bb = bx4[idx];
                    cbox2[cur ^ 1][w] = bb;
                    carea2[cur ^ 1][w] = __fmul_rn(__fsub_rn(bb.z, bb.x), __fsub_rn(bb.w, bb.y));
                    cidx2[cur ^ 1][w] = idx; cscore2[cur ^ 1][w] = __uint_as_float(uo);
                }
            }
            __syncthreads();

            u64 a0 = accmask_s[0], a1 = accmask_s[1];
            int add = __popcll(a0) + __popcll(a1);
            if (tid < m) {
                int gg = tid >> 6, o = tid & 63;
                u64 aw = (gg == 0) ? a0 : a1;
                if ((aw >> o) & 1ull) {
                    int rank = (gg > 0) ? __popcll(a0) : 0;
                    rank += __popcll(aw & ((1ull << o) - 1ull));
                    int pos = n_acc + rank;
                    if (pos < MAX_DET) {
                        abox[pos] = cbox2[cur][tid]; aarea[pos] = carea2[cur][tid];
                        si[pos] = cidx2[cur][tid]; ss[pos] = cscore2[cur][tid];
                    }
                }
            }
            n_acc += add; if (n_acc > MAX_DET) n_acc = MAX_DET;
            base = nbase; cur ^= 1;
            __syncthreads();
        }
    }

    const bool part_fb = (!full_fb) && (n_acc < MAX_DET);

    if (full_fb || part_fb) {
        // ======== exact fallback: bitmask argmax loop ========
        const int BMW = (NN + 31) / 32;
        for (int i = tid; i < BMW; i += NT) bm[i] = 0u;
        __syncthreads();
        if (full_fb) {
            n_acc = 0;
        } else {
            for (int n = tid; n < NN; n += NT) {
                float4 bbn = bx4[n];
                int s = 0;
                for (int t = 0; t < n_acc; ++t) {
                    float4 A = abox[t];
                    if (iou_gt(A.x, A.y, A.z, A.w, aarea[t],
                               bbn.x, bbn.y, bbn.z, bbn.w)) s = 1;
                }
                if (s) atomicOr(&bm[n >> 5], 1u << (n & 31));
            }
        }
        __syncthreads();

        for (int k = n_acc; k < MAX_DET; ++k) {
            float bv = neg_inf(); int bi = 0x7fffffff;
            for (int n = tid; n < NN; n += NT) {
                if (!((bm[n >> 5] >> (n & 31)) & 1u)) {
                    float v = sr[(size_t)n * NC];
                    if (v > SCORE_T && v > bv) { bv = v; bi = n; }
                }
            }
            rv[tid] = bv; ri[tid] = bi;
            __syncthreads();
            for (int s = NT / 2; s > 0; s >>= 1) {
                if (tid < s) {
                    float ov = rv[tid + s]; int oi = ri[tid + s];
                    if (ov > rv[tid] || (ov == rv[tid] && oi < ri[tid])) { rv[tid] = ov; ri[tid] = oi; }
                }
                __syncthreads();
            }
            float mval = rv[0]; int midx = ri[0];
            if (mval == neg_inf()) {
                for (int kk = k + tid; kk < MAX_DET; kk += NT) { si[kk] = 0; ss[kk] = neg_inf(); }
                break;
            }
            if (tid == 0) {
                si[k] = midx; ss[k] = mval;
                float4 sb = bx4[midx];
                sboxsh[0] = sb.x; sboxsh[1] = sb.y; sboxsh[2] = sb.z; sboxsh[3] = sb.w;
                sboxsh[4] = __fmul_rn(__fsub_rn(sb.z, sb.x), __fsub_rn(sb.w, sb.y));
            }
            __syncthreads();
            float ax1 = sboxsh[0], ay1 = sboxsh[1], ax2 = sboxsh[2], ay2 = sboxsh[3];
            float area_a = sboxsh[4];
            for (int n = tid; n < NN; n += NT) {
                float4 bbn = bx4[n];
                if (iou_gt(ax1, ay1, ax2, ay2, area_a,
                           bbn.x, bbn.y, bbn.z, bbn.w))
                    atomicOr(&bm[n >> 5], 1u << (n & 31));
            }
            __syncthreads();
        }
    } else {
        for (int kk = n_acc + tid; kk < MAX_DET; kk += NT) { si[kk] = 0; ss[kk] = neg_inf(); }
    }
}

// ---------------- T: top-300 via 8-way merge of sorted class lists --------
__global__ __launch_bounds__(1024) void topk_kernel(
    const float* __restrict__ boxes, const float* __restrict__ other,
    const int* __restrict__ sel_idx, const float* __restrict__ sel_score,
    float* __restrict__ out)
{
    const int b = blockIdx.x;
    const int tid = threadIdx.x;
    __shared__ u64 keys[4096];

    for (int i = tid; i < 4096; i += 1024) {
        int c = i >> 9, o = i & 511;
        u64 key = 0ull;
        if (o < MAX_DET) {
            int m = c * MAX_DET + o;
            float v = sel_score[b * NC * MAX_DET + m];
            unsigned u = __float_as_uint(v);
            u ^= (u & 0x80000000u) ? 0xFFFFFFFFu : 0x80000000u;
            key = ((u64)u << 32) | (unsigned)(~(unsigned)m);
        }
        keys[i] = key;
    }

    for (int seg = 1024; seg <= 4096; seg <<= 1) {
        int half = seg >> 1;
        __syncthreads();
        {
            int p = tid;
            int s = p / (half >> 1), t = p % (half >> 1);
            int i0 = s * seg + half + t;
            int i1 = s * seg + seg - 1 - t;
            u64 a = keys[i0]; keys[i0] = keys[i1]; keys[i1] = a;
        }
        __syncthreads();
        for (int j = half; j > 0; j >>= 1) {
            for (int p = tid; p < 2048; p += 1024) {
                int i = 2 * p - (p & (j - 1));
                int ix = i + j;
                u64 a = keys[i], bq = keys[ix];
                if (a < bq) { keys[i] = bq; keys[ix] = a; }
            }
            if (j >= 128) __syncthreads(); else __threadfence_block();
        }
    }
    __syncthreads();

    const float4* bx4 = (const float4*)(boxes + (size_t)b * NN * 4);
    const float*  ot  = other + (size_t)b * NN * ND;
    float* ob = out;
    float* os = out + NB * MAX_DET * 4;
    float* ol = os + NB * MAX_DET;
    float* oo = ol + NB * MAX_DET;

    for (int k = tid; k < MAX_DET; k += 1024) {
        u64 key = keys[k];
        unsigned u = (unsigned)(key >> 32);
        unsigned uo = (u & 0x80000000u) ? (u ^ 0x80000000u) : (u ^ 0xFFFFFFFFu);
        float score = __uint_as_float(uo);
        bool valid = isfinite(score);
        float b0=-1.f,b1=-1.f,b2=-1.f,b3=-1.f,scv=-1.f,lab=-1.f,o0=-1.f,o1=-1.f;
        if (valid) {
            int m = (int)(~(unsigned)key);
            int c = m / MAX_DET, slot = m - c * MAX_DET;
            int n = sel_idx[(b * NC + c) * MAX_DET + slot];
            float4 bb = bx4[n];
            b0 = bb.x; b1 = bb.y; b2 = bb.z; b3 = bb.w;
            scv = score; lab = (float)c;
            o0 = ot[n * ND + 0]; o1 = ot[n * ND + 1];
        }
        int base = b * MAX_DET + k;
        ob[base * 4 + 0] = b0; ob[base * 4 + 1] = b1;
        ob[base * 4 + 2] = b2; ob[base * 4 + 3] = b3;
        os[base] = scv; ol[base] = lab;
        oo[base * 2 + 0] = o0; oo[base * 2 + 1] = o1;
    }
}

extern "C" void kernel_launch(void* const* d_in, const int* in_sizes, int n_in,
                              void* d_out, int out_size, void* d_ws, size_t ws_size,
                              hipStream_t stream) {
    const float* boxes = (const float*)d_in[0];
    const float* cls   = (const float*)d_in[1];
    const float* other = (const float*)d_in[2];
    float* out = (float*)d_out;

    // ws: cnt_g[256 slack] | cand[128*CAP] u64 | sel_idx | sel_score
    int* cnt_g = (int*)d_ws;
    u64* cand  = (u64*)(cnt_g + NB * NC * 2);
    int* sel_idx = (int*)(cand + (size_t)NB * NC * CAP);
    float* sel_score = (float*)(sel_idx + NB * NC * MAX_DET);

    hipMemsetAsync(cnt_g, 0, NB * NC * sizeof(int), stream);
    compact_kernel<<<NB * CBLK, 1024, 0, stream>>>(cls, cnt_g, cand);
    nms_fused<<<NB * NC, NT, 0, stream>>>(boxes, cls, cand, cnt_g,
                                          sel_idx, sel_score);
    topk_kernel<<<NB, 1024, 0, stream>>>(boxes, other, sel_idx, sel_score, out);
}